// Round 9
// baseline (1344.297 us; speedup 1.0000x reference)
//
#include <hip/hip_runtime.h>
#include <hip/hip_bf16.h>

#define INV_SQRT10 0.31622776601683794f
#define INV_SQRT64 0.125f
#define INV_SQRT32 0.17677669529663687f
#define INV_SQRT96 0.10206207261596575f
#define INV_SQRT3  0.5773502691896258f

typedef __attribute__((ext_vector_type(4))) float f32x4;
typedef __attribute__((ext_vector_type(8))) short bf16x8;

__device__ __forceinline__ unsigned short f2bf(float x) {
    union { float f; unsigned u; } v; v.f = x;
    unsigned r = v.u + 0x7FFF + ((v.u >> 16) & 1);
    return (unsigned short)(r >> 16);
}
__device__ __forceinline__ float bf2f(unsigned short u) {
    union { unsigned u; float f; } v; v.u = ((unsigned)u) << 16;
    return v.f;
}

// ---------------------------------------------------------------------------
// prep: node features -> bf16 (xs N x 64; xvp plane-major) + degree count
// ---------------------------------------------------------------------------
__global__ __launch_bounds__(256) void k_prep_nodes(
    const float* __restrict__ ns, const float* __restrict__ nv,
    const int* __restrict__ dst,
    unsigned short* __restrict__ xsb, unsigned short* __restrict__ xvpb,
    int* __restrict__ cnt, int N, int E)
{
    const int gid = blockIdx.x * 256 + threadIdx.x, gs = gridDim.x * 256;
    for (int i = gid; i < N * 64; i += gs) xsb[i] = f2bf(ns[i]);
    for (int i = gid; i < N * 96; i += gs) {
        const int n = i / 96, rem = i - n * 96;
        const int ic = rem >> 5, u = rem & 31;
        xvpb[i] = f2bf(nv[(size_t)n * 96 + u * 3 + ic]);
    }
    for (int i = gid; i < E; i += gs) atomicAdd(&cnt[dst[i]], 1);
}

// ---------------------------------------------------------------------------
// prep: weights -> bf16 panels.
// ---------------------------------------------------------------------------
template <int OS>
__global__ __launch_bounds__(256) void k_prep_w(
    const float* __restrict__ Wl1s, const float* __restrict__ Wscs,
    const float* __restrict__ Wl1v, const float* __restrict__ Wscv,
    const float* __restrict__ Wfc2,
    const float* __restrict__ W2s, const float* __restrict__ W2v,
    const float* __restrict__ Wa,
    unsigned short* __restrict__ wsb, unsigned short* __restrict__ wvb,
    unsigned short* __restrict__ wfb,
    unsigned short* __restrict__ wob, unsigned short* __restrict__ wv2b)
{
    constexpr int NC1 = 64 + OS;
    constexpr int PC1 = ((OS + 16 + 15) / 16) * 16;   // 112 (OS=96) / 80 (OS=64)
    const int gid = blockIdx.x * 256 + threadIdx.x, gs = gridDim.x * 256;
    for (int i = gid; i < NC1 * 64; i += gs) {
        const int c = i >> 6, k = i & 63;
        const float v = (c < 64) ? Wl1s[k * 64 + c] : Wscs[k * OS + (c - 64)];
        wsb[i] = f2bf(v);
    }
    for (int i = gid; i < 64 * 32; i += gs) {
        const int c = i >> 5, u = i & 31;
        const float v = (c < 32) ? Wl1v[u * 32 + c] : Wscv[u * 32 + (c - 32)];
        wvb[i] = f2bf(v);
    }
    for (int i = gid; i < 192 * 64; i += gs) {
        const int c = i >> 6, k = i & 63;
        wfb[i] = f2bf(Wfc2[k * 192 + c]);
    }
    for (int i = gid; i < PC1 * 96; i += gs) {
        const int c = i / 96, u = i - c * 96;
        float v = 0.f;
        if (c < OS) v = W2s[u * OS + c];
        else if (c == OS) v = Wa[u];
        wob[i] = f2bf(v);
    }
    for (int i = gid; i < 32 * 96; i += gs) {
        const int c = i / 96, u = i - c * 96;
        wv2b[i] = f2bf(W2v[u * 32 + c]);
    }
}

// ---------------------------------------------------------------------------
// Hierarchical exclusive scan of cnt -> base.
// ---------------------------------------------------------------------------
__global__ __launch_bounds__(256) void k_scan1(const int* __restrict__ cnt,
                                               int* __restrict__ partial, int N)
{
    __shared__ int lds[256];
    const int t = threadIdx.x, i = blockIdx.x * 256 + t;
    int v = (i < N) ? cnt[i] : 0;
    lds[t] = v;
    __syncthreads();
    for (int off = 128; off > 0; off >>= 1) {
        if (t < off) lds[t] += lds[t + off];
        __syncthreads();
    }
    if (t == 0) partial[blockIdx.x] = lds[0];
}

__global__ __launch_bounds__(1024) void k_scan2(int* __restrict__ partial, int NB)
{
    __shared__ int lds[1024];
    const int t = threadIdx.x;
    int v = (t < NB) ? partial[t] : 0;
    lds[t] = v;
    __syncthreads();
    for (int off = 1; off < 1024; off <<= 1) {
        int w = (t >= off) ? lds[t - off] : 0;
        __syncthreads();
        lds[t] += w;
        __syncthreads();
    }
    if (t < NB) partial[t] = lds[t] - v;   // exclusive
}

__global__ __launch_bounds__(256) void k_scan3(const int* __restrict__ cnt,
                                               const int* __restrict__ partial,
                                               int* __restrict__ base, int N)
{
    __shared__ int lds[256];
    const int t = threadIdx.x, i = blockIdx.x * 256 + t;
    int v = (i < N) ? cnt[i] : 0;
    lds[t] = v;
    __syncthreads();
    for (int off = 1; off < 256; off <<= 1) {
        int w = (t >= off) ? lds[t - off] : 0;
        __syncthreads();
        lds[t] += w;
        __syncthreads();
    }
    if (i < N) base[i] = partial[blockIdx.x] + lds[t] - v;
}

// ---------------------------------------------------------------------------
// scatter: materialize CSR-ordered src / sh (f32) / esc (bf16).
// ---------------------------------------------------------------------------
__global__ __launch_bounds__(256) void k_scatter(
    const int* __restrict__ src, const int* __restrict__ dst,
    const float* __restrict__ sh, const float* __restrict__ esc,
    const int* __restrict__ base, int* __restrict__ cursor,
    int* __restrict__ src_ord, float4* __restrict__ sh_ord,
    unsigned short* __restrict__ esc_ordb, int E)
{
    int i = blockIdx.x * 256 + threadIdx.x;
    if (i < E) {
        const int d = dst[i];
        const int pos = base[d] + atomicAdd(&cursor[d], 1);
        src_ord[pos] = src[i];
        sh_ord[pos] = ((const float4*)sh)[i];
        const float* ep = esc + (size_t)i * 10;
        unsigned short* eo = esc_ordb + (size_t)pos * 10;
        #pragma unroll
        for (int q = 0; q < 10; q++) eo[q] = f2bf(ep[q]);
    }
}

// ---------------------------------------------------------------------------
// K1: node linears, register-only MFMA. 64 nodes/block, 4 waves.
// ---------------------------------------------------------------------------
template <int OS>
__global__ __launch_bounds__(256) void k_node_mfma(
    const unsigned short* __restrict__ xsb, const unsigned short* __restrict__ xvpb,
    const float* __restrict__ attr,
    const unsigned short* __restrict__ wsb, const unsigned short* __restrict__ wvb,
    unsigned short* __restrict__ hsb, unsigned short* __restrict__ hvbb,
    float* __restrict__ scs, float* __restrict__ scv, int N)
{
    constexpr int NC1 = 64 + OS;
    constexpr int CT1 = NC1 / 16;
    __shared__ float attr_l[64];
    const int tid = threadIdx.x;
    const int n0 = blockIdx.x * 64;
    if (tid < 64) attr_l[tid] = (n0 + tid < N) ? attr[n0 + tid] : 0.f;
    __syncthreads();
    const int wv = tid >> 6, lane = tid & 63;
    const int mrow = lane & 15, kg = lane >> 4;

    {
        const int rbase = wv * 16;
        const int r = rbase + mrow;
        const int rc = min(n0 + r, N - 1);
        const bf16x8 a0 = *(const bf16x8*)(xsb + (size_t)rc * 64 + kg * 8);
        const bf16x8 a1 = *(const bf16x8*)(xsb + (size_t)rc * 64 + 32 + kg * 8);
        f32x4 acc[CT1];
        #pragma unroll
        for (int t = 0; t < CT1; t++) acc[t] = (f32x4){0.f, 0.f, 0.f, 0.f};
        #pragma unroll
        for (int t = 0; t < CT1; t++) {
            const int c = t * 16 + mrow;
            const bf16x8 b0 = *(const bf16x8*)(wsb + c * 64 + kg * 8);
            const bf16x8 b1 = *(const bf16x8*)(wsb + c * 64 + 32 + kg * 8);
            acc[t] = __builtin_amdgcn_mfma_f32_16x16x32_bf16(a0, b0, acc[t], 0, 0, 0);
            acc[t] = __builtin_amdgcn_mfma_f32_16x16x32_bf16(a1, b1, acc[t], 0, 0, 0);
        }
        #pragma unroll
        for (int t = 0; t < CT1; t++) {
            const int c = t * 16 + mrow;
            #pragma unroll
            for (int rg = 0; rg < 4; rg++) {
                const int row = rbase + kg * 4 + rg;
                const int n = n0 + row;
                if (n < N) {
                    const float v = acc[t][rg] * INV_SQRT64 * attr_l[row];
                    if (c < 64) hsb[(size_t)n * 64 + c] = f2bf(v);
                    else        scs[(size_t)n * OS + (c - 64)] = v;
                }
            }
        }
    }
    #pragma unroll
    for (int j = 0; j < 3; j++) {
        const int rbase = (wv * 3 + j) * 16;
        const int rv = rbase + mrow;
        const int ic = rv >> 6, nloc = rv & 63;
        const int nc = min(n0 + nloc, N - 1);
        const bf16x8 a = *(const bf16x8*)(xvpb + (size_t)nc * 96 + ic * 32 + kg * 8);
        f32x4 acc2[4];
        #pragma unroll
        for (int t = 0; t < 4; t++) acc2[t] = (f32x4){0.f, 0.f, 0.f, 0.f};
        #pragma unroll
        for (int t = 0; t < 4; t++) {
            const int c = t * 16 + mrow;
            const bf16x8 b = *(const bf16x8*)(wvb + c * 32 + kg * 8);
            acc2[t] = __builtin_amdgcn_mfma_f32_16x16x32_bf16(a, b, acc2[t], 0, 0, 0);
        }
        #pragma unroll
        for (int t = 0; t < 4; t++) {
            const int c = t * 16 + mrow;
            #pragma unroll
            for (int rg = 0; rg < 4; rg++) {
                const int rv2 = rbase + kg * 4 + rg;
                const int ic2 = rv2 >> 6, nl = rv2 & 63;
                const int n = n0 + nl;
                if (n < N) {
                    const float v = acc2[t][rg] * INV_SQRT32 * attr_l[nl];
                    if (c < 32) hvbb[(size_t)n * 96 + ic2 * 32 + c] = f2bf(v);
                    else        scv[(size_t)n * 96 + ic2 * 32 + (c - 32)] = v;
                }
            }
        }
    }
}

// ---------------------------------------------------------------------------
// K2: FUSED edge MLP + aggregation. 8 nodes/block, 4 waves (2 nodes/wave).
//   Per 64-edge chunk of the block's CSR range:
//     stage esc -> h = silu(esc@Wfc1/sqrt10) -> hb (bf16 LDS, swizzled)
//     MFMA w = h @ wfb / sqrt64 -> w_l LDS, permuted col' = (c&15)*12 + (c>>4)
//     each wave aggregates its nodes' edges within the chunk (w from LDS).
//   No global w traffic, no atomics.
// ---------------------------------------------------------------------------
__global__ __launch_bounds__(256) void k_agg_fused(
    const unsigned short* __restrict__ hsb, const unsigned short* __restrict__ hvbb,
    const int* __restrict__ src_ord, const float4* __restrict__ sh_ord,
    const unsigned short* __restrict__ esc_ordb,
    const int* __restrict__ base, const int* __restrict__ cnt,
    const float* __restrict__ Wfc1, const unsigned short* __restrict__ wfb,
    unsigned short* __restrict__ Msb, unsigned short* __restrict__ Mvb,
    int N, int E)
{
    __shared__ float w1_l[640];
    __shared__ float esc_l[640];
    __shared__ __align__(16) char hb[64 * 64 * 2];          // [row][k] bf16 ^((r&7)<<4)
    __shared__ __align__(16) unsigned short w_l[64 * 192];  // [row][col']
    const int tid = threadIdx.x;
    const int n0 = blockIdx.x * 8;
    if (n0 >= N) return;
    const int wv = tid >> 6, lane = tid & 63;
    const int mrow = lane & 15, kgrp = lane >> 4;

    for (int i = tid; i < 640; i += 256) w1_l[i] = Wfc1[i];

    const int eb0 = base[n0];
    const int eb1 = (n0 + 8 >= N) ? E : base[n0 + 8];

    // wave's two nodes
    const int nA = n0 + 2 * wv, nB = nA + 1;
    const bool vA = nA < N, vB = nB < N;
    const int bA = vA ? base[nA] : 0, cA = vA ? cnt[nA] : 0;
    const int bB = vB ? base[nB] : 0, cB_ = vB ? cnt[nB] : 0;

    float accA[8] = {0.f, 0.f, 0.f, 0.f, 0.f, 0.f, 0.f, 0.f};
    float accB[8] = {0.f, 0.f, 0.f, 0.f, 0.f, 0.f, 0.f, 0.f};
    // 0=aS 1=aSB 2=aV0 3=aV1 4=aV2 5=aB0 6=aB1 7=aB2

    const int colB = (lane < 32) ? (128 + lane) : (160 + lane - 32);
    const int pc1 = (lane & 15) * 12 + (lane >> 4);
    const int pc2 = ((64 + lane) & 15) * 12 + ((64 + lane) >> 4);
    const int pc3 = (colB & 15) * 12 + (colB >> 4);

    for (int ck = eb0; ck < eb1; ck += 64) {
        const int nval = min(64, eb1 - ck);
        if (ck > eb0) __syncthreads();   // protect LDS reuse
        // ---- stage esc (contiguous)
        {
            const size_t emax = (size_t)E * 10 - 1;
            const size_t sbase = (size_t)ck * 10;
            for (int i = tid; i < 640; i += 256) {
                size_t idx = sbase + i;
                esc_l[i] = bf2f(esc_ordb[idx > emax ? emax : idx]);
            }
        }
        __syncthreads();
        // ---- h: thread -> edge r=tid>>2, cols c0=(tid&3)*16
        {
            const int r = tid >> 2, c0 = (tid & 3) << 4;
            float hval[16];
            #pragma unroll
            for (int c = 0; c < 16; c++) {
                float acc = 0.f;
                #pragma unroll
                for (int q = 0; q < 10; q++) acc += esc_l[r * 10 + q] * w1_l[q * 64 + c0 + c];
                acc *= INV_SQRT10;
                hval[c] = acc / (1.f + __expf(-acc));
            }
            unsigned pk[8];
            #pragma unroll
            for (int j = 0; j < 8; j++)
                pk[j] = (unsigned)f2bf(hval[2 * j]) | ((unsigned)f2bf(hval[2 * j + 1]) << 16);
            const int swz = (r & 7) << 4;
            const int b0 = (r << 7) + (c0 << 1);
            *(uint4*)(hb + (b0 ^ swz)) = make_uint4(pk[0], pk[1], pk[2], pk[3]);
            *(uint4*)(hb + ((b0 + 16) ^ swz)) = make_uint4(pk[4], pk[5], pk[6], pk[7]);
        }
        __syncthreads();
        // ---- MFMA: wave wv -> rows [wv*16, +16), 12 col-tiles, K=64
        {
            f32x4 acc[12];
            #pragma unroll
            for (int t = 0; t < 12; t++) acc[t] = (f32x4){0.f, 0.f, 0.f, 0.f};
            #pragma unroll
            for (int kc = 0; kc < 2; kc++) {
                const int r = wv * 16 + mrow;
                const int abyte = ((r << 7) + (kc << 6) + (kgrp << 4)) ^ ((r & 7) << 4);
                const bf16x8 afrag = *(const bf16x8*)(hb + abyte);
                #pragma unroll
                for (int t = 0; t < 12; t++) {
                    const int c = t * 16 + mrow;
                    const bf16x8 bfrag = *(const bf16x8*)(wfb + c * 64 + kc * 32 + kgrp * 8);
                    acc[t] = __builtin_amdgcn_mfma_f32_16x16x32_bf16(afrag, bfrag, acc[t], 0, 0, 0);
                }
            }
            // w_l write: row = wv*16 + kgrp*4 + rg; cols' mrow*12 + tb (tb=0..11)
            #pragma unroll
            for (int rg = 0; rg < 4; rg++) {
                const int row = wv * 16 + kgrp * 4 + rg;
                const int off = row * 192 + mrow * 12;
                ushort4 q0, q1, q2;
                q0.x = f2bf(acc[0][rg] * INV_SQRT64);  q0.y = f2bf(acc[1][rg] * INV_SQRT64);
                q0.z = f2bf(acc[2][rg] * INV_SQRT64);  q0.w = f2bf(acc[3][rg] * INV_SQRT64);
                q1.x = f2bf(acc[4][rg] * INV_SQRT64);  q1.y = f2bf(acc[5][rg] * INV_SQRT64);
                q1.z = f2bf(acc[6][rg] * INV_SQRT64);  q1.w = f2bf(acc[7][rg] * INV_SQRT64);
                q2.x = f2bf(acc[8][rg] * INV_SQRT64);  q2.y = f2bf(acc[9][rg] * INV_SQRT64);
                q2.z = f2bf(acc[10][rg] * INV_SQRT64); q2.w = f2bf(acc[11][rg] * INV_SQRT64);
                *(ushort4*)(w_l + off) = q0;
                *(ushort4*)(w_l + off + 4) = q1;
                *(ushort4*)(w_l + off + 8) = q2;
            }
        }
        __syncthreads();
        // ---- aggregate this chunk's edges for the wave's two nodes
        #pragma unroll
        for (int half = 0; half < 2; half++) {
            float* acc = half ? accB : accA;
            const int b_ = half ? bB : bA;
            const int c_ = half ? cB_ : cA;
            const bool v_ = half ? vB : vA;
            if (!v_) continue;
            const int j0 = max(b_, ck) - ck;
            const int j1 = min(b_ + c_, ck + nval) - ck;
            for (int j = j0; j < j1; ++j) {
                const int pos = ck + j;
                const int s = src_ord[pos];
                const float w1 = bf2f(w_l[j * 192 + pc1]);
                const float w2 = bf2f(w_l[j * 192 + pc2]);
                const float wB = bf2f(w_l[j * 192 + pc3]);
                const float gs = bf2f(hsb[(size_t)s * 64 + lane]);
                float gv0 = 0.f, gv1 = 0.f, gv2 = 0.f;
                if (lane < 32) {
                    gv0 = bf2f(hvbb[(size_t)s * 96 + lane]);
                    gv1 = bf2f(hvbb[(size_t)s * 96 + 32 + lane]);
                    gv2 = bf2f(hvbb[(size_t)s * 96 + 64 + lane]);
                }
                const float4 s4 = sh_ord[pos];
                const float gvdot = gv0 * s4.y + gv1 * s4.z + gv2 * s4.w;
                const float gvd = __shfl(gvdot, lane & 31);
                acc[0] += gs * s4.x * w1;
                acc[1] += gvd * INV_SQRT3 * wB;
                acc[2] += gs * s4.y * w2;
                acc[3] += gs * s4.z * w2;
                acc[4] += gs * s4.w * w2;
                acc[5] += gv0 * s4.x * wB;
                acc[6] += gv1 * s4.x * wB;
                acc[7] += gv2 * s4.x * wB;
            }
        }
    }
    // ---- write out the wave's two nodes
    #pragma unroll
    for (int half = 0; half < 2; half++) {
        const float* acc = half ? accB : accA;
        const int n = half ? nB : nA;
        const int c_ = half ? cB_ : cA;
        const bool v_ = half ? vB : vA;
        if (!v_) continue;
        const float invd = 1.f / (float)max(c_, 1);
        unsigned short* msp = Msb + (size_t)n * 96;
        unsigned short* mvp = Mvb + (size_t)n * 3 * 96;
        msp[lane] = f2bf(acc[0] * invd);
        if (lane >= 32) msp[64 + (lane - 32)] = f2bf(acc[1] * invd);
        mvp[0 * 96 + lane] = f2bf(acc[2] * invd);
        mvp[1 * 96 + lane] = f2bf(acc[3] * invd);
        mvp[2 * 96 + lane] = f2bf(acc[4] * invd);
        if (lane < 32) {
            mvp[0 * 96 + 64 + lane] = f2bf(acc[5] * invd);
            mvp[1 * 96 + 64 + lane] = f2bf(acc[6] * invd);
            mvp[2 * 96 + 64 + lane] = f2bf(acc[7] * invd);
        }
    }
}

// ---------------------------------------------------------------------------
// K3: node finalize as MFMA. 64 nodes/block, 4 waves.
// ---------------------------------------------------------------------------
template <int OS, bool FINAL>
__global__ __launch_bounds__(256) void k_node_out(
    const unsigned short* __restrict__ Msb, const unsigned short* __restrict__ Mvb,
    const float* __restrict__ attr,
    const float* __restrict__ scs, const float* __restrict__ scv,
    const unsigned short* __restrict__ wob, const unsigned short* __restrict__ wv2b,
    float* __restrict__ outF,
    unsigned short* __restrict__ outSb, unsigned short* __restrict__ outVb, int N)
{
    constexpr int CT1 = (OS + 16 + 15) / 16;   // 7 (OS=96) / 5 (OS=64)
    constexpr int TA = OS / 16;                // tile holding alpha col (mrow==0)
    __shared__ float attr_l[64];
    __shared__ float alpha_l[64];
    __shared__ float gate_l[64][32];
    const int tid = threadIdx.x;
    const int n0 = blockIdx.x * 64;
    if (tid < 64) attr_l[tid] = (n0 + tid < N) ? attr[n0 + tid] : 0.f;
    __syncthreads();
    const int wv = tid >> 6, lane = tid & 63;
    const int mrow = lane & 15, kg = lane >> 4;

    // ---- GEMM1
    const int rbase = wv * 16;
    const int rc = min(n0 + rbase + mrow, N - 1);
    f32x4 acc[CT1];
    #pragma unroll
    for (int t = 0; t < CT1; t++) acc[t] = (f32x4){0.f, 0.f, 0.f, 0.f};
    #pragma unroll
    for (int kc = 0; kc < 3; kc++) {
        const bf16x8 a = *(const bf16x8*)(Msb + (size_t)rc * 96 + kc * 32 + kg * 8);
        #pragma unroll
        for (int t = 0; t < CT1; t++) {
            const bf16x8 b = *(const bf16x8*)(wob + (size_t)(t * 16 + mrow) * 96 + kc * 32 + kg * 8);
            acc[t] = __builtin_amdgcn_mfma_f32_16x16x32_bf16(a, b, acc[t], 0, 0, 0);
        }
    }
    if (mrow == 0) {
        #pragma unroll
        for (int rg = 0; rg < 4; rg++) {
            const int row = rbase + kg * 4 + rg;
            alpha_l[row] = acc[TA][rg] * INV_SQRT96 * attr_l[row];
        }
    }
    __syncthreads();
    // ---- epilogue 1
    #pragma unroll
    for (int t = 0; t < CT1; t++) {
        const int c = t * 16 + mrow;
        if (c < OS) {
            #pragma unroll
            for (int rg = 0; rg < 4; rg++) {
                const int row = rbase + kg * 4 + rg;
                const int n = n0 + row;
                if (n < N) {
                    const float os = acc[t][rg] * INV_SQRT96 * attr_l[row];
                    const float s = scs[(size_t)n * OS + c] + alpha_l[row] * os;
                    if (FINAL) {
                        outF[(size_t)n * 160 + c] = s;
                    } else {
                        if (c < 64) outSb[(size_t)n * 64 + c] = f2bf(s / (1.f + __expf(-s)));
                        else        gate_l[row][c - 64] = 1.f / (1.f + __expf(-s));
                    }
                }
            }
        }
    }
    __syncthreads();
    // ---- GEMM2: rows rv = nloc*3+i (192), wave handles 3 row-tiles
    #pragma unroll
    for (int j = 0; j < 3; j++) {
        const int rb2 = (wv * 3 + j) * 16;
        const int rv = rb2 + mrow;
        const int nl = rv / 3, ii = rv - nl * 3;
        const int nc2 = min(n0 + nl, N - 1);
        f32x4 acc2[2];
        acc2[0] = (f32x4){0.f, 0.f, 0.f, 0.f};
        acc2[1] = (f32x4){0.f, 0.f, 0.f, 0.f};
        #pragma unroll
        for (int kc = 0; kc < 3; kc++) {
            const bf16x8 a = *(const bf16x8*)(Mvb + ((size_t)nc2 * 3 + ii) * 96 + kc * 32 + kg * 8);
            #pragma unroll
            for (int t = 0; t < 2; t++) {
                const bf16x8 b = *(const bf16x8*)(wv2b + (size_t)(t * 16 + mrow) * 96 + kc * 32 + kg * 8);
                acc2[t] = __builtin_amdgcn_mfma_f32_16x16x32_bf16(a, b, acc2[t], 0, 0, 0);
            }
        }
        #pragma unroll
        for (int t = 0; t < 2; t++) {
            const int k = t * 16 + mrow;
            #pragma unroll
            for (int rg = 0; rg < 4; rg++) {
                const int rv2 = rb2 + kg * 4 + rg;
                const int nl2 = rv2 / 3, i2 = rv2 - nl2 * 3;
                const int n = n0 + nl2;
                if (n < N) {
                    const float ov = acc2[t][rg] * INV_SQRT96 * attr_l[nl2];
                    const float v = scv[(size_t)n * 96 + i2 * 32 + k] + alpha_l[nl2] * ov;
                    if (FINAL) outF[(size_t)n * 160 + 64 + k * 3 + i2] = v;
                    else       outVb[(size_t)n * 96 + i2 * 32 + k] = f2bf(v * gate_l[nl2][k]);
                }
            }
        }
    }
}

// ---------------------------------------------------------------------------
extern "C" void kernel_launch(void* const* d_in, const int* in_sizes, int n_in,
                              void* d_out, int out_size, void* d_ws, size_t ws_size,
                              hipStream_t stream)
{
    const float* node_s = (const float*)d_in[0];
    const float* node_v = (const float*)d_in[1];
    const float* attr   = (const float*)d_in[2];
    const int*   esrc   = (const int*)d_in[3];
    const int*   edst   = (const int*)d_in[4];
    const float* esh    = (const float*)d_in[5];
    const float* esc    = (const float*)d_in[6];
    const float* W[18];
    for (int i = 0; i < 18; i++) W[i] = (const float*)d_in[7 + i];
    // per layer: 0 sc_s, 1 sc_v, 2 lin1_s, 3 lin1_v, 4 fc1, 5 fc2, 6 lin2_s, 7 lin2_v, 8 alpha

    const int N = in_sizes[0] / 64;
    const int E = in_sizes[3];
    const int NB = (N + 255) / 256;

    char* p = (char*)d_ws;
    unsigned short* xsb  = (unsigned short*)p; p += (size_t)N * 64 * 2;
    unsigned short* xvpb = (unsigned short*)p; p += (size_t)N * 96 * 2;
    unsigned short* hsb  = (unsigned short*)p; p += (size_t)N * 64 * 2;
    unsigned short* hvbb = (unsigned short*)p; p += (size_t)N * 96 * 2;
    unsigned short* Msb  = (unsigned short*)p; p += (size_t)N * 96 * 2;
    unsigned short* Mvb  = (unsigned short*)p; p += (size_t)N * 288 * 2;
    float* scs = (float*)p; p += (size_t)N * 96 * 4;
    float* scv = (float*)p; p += (size_t)N * 96 * 4;
    unsigned short* wsb1 = (unsigned short*)p; p += 160 * 64 * 2;
    unsigned short* wsb2 = (unsigned short*)p; p += 128 * 64 * 2;
    unsigned short* wvb1 = (unsigned short*)p; p += 64 * 32 * 2;
    unsigned short* wvb2 = (unsigned short*)p; p += 64 * 32 * 2;
    unsigned short* wfb1 = (unsigned short*)p; p += 192 * 64 * 2;
    unsigned short* wfb2 = (unsigned short*)p; p += 192 * 64 * 2;
    unsigned short* wob1 = (unsigned short*)p; p += 112 * 96 * 2;
    unsigned short* wob2 = (unsigned short*)p; p += 80 * 96 * 2;
    unsigned short* wv2b1 = (unsigned short*)p; p += 32 * 96 * 2;
    unsigned short* wv2b2 = (unsigned short*)p; p += 32 * 96 * 2;
    int* cnt    = (int*)p; p += (size_t)N * 4;
    int* cursor = (int*)p; p += (size_t)N * 4;
    int* basei  = (int*)p; p += (size_t)N * 4;
    int* partial = (int*)p; p += (size_t)NB * 4;
    p = (char*)(((size_t)p + 255) & ~(size_t)255);
    int* src_ord = (int*)p; p += (size_t)E * 4;
    p = (char*)(((size_t)p + 15) & ~(size_t)15);
    float4* sh_ord = (float4*)p; p += (size_t)E * 16;
    unsigned short* esc_ordb = (unsigned short*)p; p += (size_t)E * 20;

    const int nb  = (N + 63) / 64;
    const int ebk = (E + 255) / 256;
    const int fb  = (N + 7) / 8;

    // ---- prep + CSR build
    hipMemsetAsync(cnt, 0, (size_t)2 * N * sizeof(int), stream);  // cnt + cursor
    k_prep_nodes<<<2048, 256, 0, stream>>>(node_s, node_v, edst, xsb, xvpb, cnt, N, E);
    k_prep_w<96><<<32, 256, 0, stream>>>(W[2], W[0], W[3], W[1], W[5], W[6], W[7], W[8],
                                         wsb1, wvb1, wfb1, wob1, wv2b1);
    k_prep_w<64><<<32, 256, 0, stream>>>(W[11], W[9], W[12], W[10], W[14], W[15], W[16], W[17],
                                         wsb2, wvb2, wfb2, wob2, wv2b2);
    k_scan1<<<NB, 256, 0, stream>>>(cnt, partial, N);
    k_scan2<<<1, 1024, 0, stream>>>(partial, NB);
    k_scan3<<<NB, 256, 0, stream>>>(cnt, partial, basei, N);
    k_scatter<<<ebk, 256, 0, stream>>>(esrc, edst, esh, esc, basei, cursor,
                                       src_ord, sh_ord, esc_ordb, E);

    // ---- layer 1
    k_node_mfma<96><<<nb, 256, 0, stream>>>(xsb, xvpb, attr, wsb1, wvb1,
                                            hsb, hvbb, scs, scv, N);
    k_agg_fused<<<fb, 256, 0, stream>>>(hsb, hvbb, src_ord, sh_ord, esc_ordb,
                                        basei, cnt, W[4], wfb1, Msb, Mvb, N, E);
    k_node_out<96, false><<<nb, 256, 0, stream>>>(Msb, Mvb, attr, scs, scv,
                                                  wob1, wv2b1,
                                                  nullptr, xsb, xvpb, N);
    // ---- layer 2
    k_node_mfma<64><<<nb, 256, 0, stream>>>(xsb, xvpb, attr, wsb2, wvb2,
                                            hsb, hvbb, scs, scv, N);
    k_agg_fused<<<fb, 256, 0, stream>>>(hsb, hvbb, src_ord, sh_ord, esc_ordb,
                                        basei, cnt, W[13], wfb2, Msb, Mvb, N, E);
    k_node_out<64, true><<<nb, 256, 0, stream>>>(Msb, Mvb, attr, scs, scv,
                                                 wob2, wv2b2,
                                                 (float*)d_out, nullptr, nullptr, N);
}

// Round 10
// 661.303 us; speedup vs baseline: 2.0328x; 2.0328x over previous
//
#include <hip/hip_runtime.h>
#include <hip/hip_bf16.h>

#define INV_SQRT10 0.31622776601683794f
#define INV_SQRT64 0.125f
#define INV_SQRT32 0.17677669529663687f
#define INV_SQRT96 0.10206207261596575f
#define INV_SQRT3  0.5773502691896258f

typedef __attribute__((ext_vector_type(4))) float f32x4;
typedef __attribute__((ext_vector_type(8))) short bf16x8;

__device__ __forceinline__ unsigned short f2bf(float x) {
    union { float f; unsigned u; } v; v.f = x;
    unsigned r = v.u + 0x7FFF + ((v.u >> 16) & 1);
    return (unsigned short)(r >> 16);
}
__device__ __forceinline__ float bf2f(unsigned short u) {
    union { unsigned u; float f; } v; v.u = ((unsigned)u) << 16;
    return v.f;
}

// ---------------------------------------------------------------------------
// prep: node features -> bf16 (xs N x 64; xvp plane-major) + degree count
// ---------------------------------------------------------------------------
__global__ __launch_bounds__(256) void k_prep_nodes(
    const float* __restrict__ ns, const float* __restrict__ nv,
    const int* __restrict__ dst,
    unsigned short* __restrict__ xsb, unsigned short* __restrict__ xvpb,
    int* __restrict__ cnt, int N, int E)
{
    const int gid = blockIdx.x * 256 + threadIdx.x, gs = gridDim.x * 256;
    for (int i = gid; i < N * 64; i += gs) xsb[i] = f2bf(ns[i]);
    for (int i = gid; i < N * 96; i += gs) {
        const int n = i / 96, rem = i - n * 96;
        const int ic = rem >> 5, u = rem & 31;
        xvpb[i] = f2bf(nv[(size_t)n * 96 + u * 3 + ic]);
    }
    for (int i = gid; i < E; i += gs) atomicAdd(&cnt[dst[i]], 1);
}

// ---------------------------------------------------------------------------
// prep: weights -> bf16 panels.
// ---------------------------------------------------------------------------
template <int OS>
__global__ __launch_bounds__(256) void k_prep_w(
    const float* __restrict__ Wl1s, const float* __restrict__ Wscs,
    const float* __restrict__ Wl1v, const float* __restrict__ Wscv,
    const float* __restrict__ Wfc2,
    const float* __restrict__ W2s, const float* __restrict__ W2v,
    const float* __restrict__ Wa,
    unsigned short* __restrict__ wsb, unsigned short* __restrict__ wvb,
    unsigned short* __restrict__ wfb,
    unsigned short* __restrict__ wob, unsigned short* __restrict__ wv2b)
{
    constexpr int NC1 = 64 + OS;
    constexpr int PC1 = ((OS + 16 + 15) / 16) * 16;   // 112 (OS=96) / 80 (OS=64)
    const int gid = blockIdx.x * 256 + threadIdx.x, gs = gridDim.x * 256;
    for (int i = gid; i < NC1 * 64; i += gs) {
        const int c = i >> 6, k = i & 63;
        const float v = (c < 64) ? Wl1s[k * 64 + c] : Wscs[k * OS + (c - 64)];
        wsb[i] = f2bf(v);
    }
    for (int i = gid; i < 64 * 32; i += gs) {
        const int c = i >> 5, u = i & 31;
        const float v = (c < 32) ? Wl1v[u * 32 + c] : Wscv[u * 32 + (c - 32)];
        wvb[i] = f2bf(v);
    }
    for (int i = gid; i < 192 * 64; i += gs) {
        const int c = i >> 6, k = i & 63;
        wfb[i] = f2bf(Wfc2[k * 192 + c]);
    }
    for (int i = gid; i < PC1 * 96; i += gs) {
        const int c = i / 96, u = i - c * 96;
        float v = 0.f;
        if (c < OS) v = W2s[u * OS + c];
        else if (c == OS) v = Wa[u];
        wob[i] = f2bf(v);
    }
    for (int i = gid; i < 32 * 96; i += gs) {
        const int c = i / 96, u = i - c * 96;
        wv2b[i] = f2bf(W2v[u * 32 + c]);
    }
}

// ---------------------------------------------------------------------------
// Hierarchical exclusive scan of cnt -> base.
// ---------------------------------------------------------------------------
__global__ __launch_bounds__(256) void k_scan1(const int* __restrict__ cnt,
                                               int* __restrict__ partial, int N)
{
    __shared__ int lds[256];
    const int t = threadIdx.x, i = blockIdx.x * 256 + t;
    int v = (i < N) ? cnt[i] : 0;
    lds[t] = v;
    __syncthreads();
    for (int off = 128; off > 0; off >>= 1) {
        if (t < off) lds[t] += lds[t + off];
        __syncthreads();
    }
    if (t == 0) partial[blockIdx.x] = lds[0];
}

__global__ __launch_bounds__(1024) void k_scan2(int* __restrict__ partial, int NB)
{
    __shared__ int lds[1024];
    const int t = threadIdx.x;
    int v = (t < NB) ? partial[t] : 0;
    lds[t] = v;
    __syncthreads();
    for (int off = 1; off < 1024; off <<= 1) {
        int w = (t >= off) ? lds[t - off] : 0;
        __syncthreads();
        lds[t] += w;
        __syncthreads();
    }
    if (t < NB) partial[t] = lds[t] - v;   // exclusive
}

__global__ __launch_bounds__(256) void k_scan3(const int* __restrict__ cnt,
                                               const int* __restrict__ partial,
                                               int* __restrict__ base, int N)
{
    __shared__ int lds[256];
    const int t = threadIdx.x, i = blockIdx.x * 256 + t;
    int v = (i < N) ? cnt[i] : 0;
    lds[t] = v;
    __syncthreads();
    for (int off = 1; off < 256; off <<= 1) {
        int w = (t >= off) ? lds[t - off] : 0;
        __syncthreads();
        lds[t] += w;
        __syncthreads();
    }
    if (i < N) base[i] = partial[blockIdx.x] + lds[t] - v;
}

// ---------------------------------------------------------------------------
// scatter: materialize CSR-ordered src / sh (f32) / esc (bf16).
// ---------------------------------------------------------------------------
__global__ __launch_bounds__(256) void k_scatter(
    const int* __restrict__ src, const int* __restrict__ dst,
    const float* __restrict__ sh, const float* __restrict__ esc,
    const int* __restrict__ base, int* __restrict__ cursor,
    int* __restrict__ src_ord, float4* __restrict__ sh_ord,
    unsigned short* __restrict__ esc_ordb, int E)
{
    int i = blockIdx.x * 256 + threadIdx.x;
    if (i < E) {
        const int d = dst[i];
        const int pos = base[d] + atomicAdd(&cursor[d], 1);
        src_ord[pos] = src[i];
        sh_ord[pos] = ((const float4*)sh)[i];
        const float* ep = esc + (size_t)i * 10;
        unsigned short* eo = esc_ordb + (size_t)pos * 10;
        #pragma unroll
        for (int q = 0; q < 10; q++) eo[q] = f2bf(ep[q]);
    }
}

// ---------------------------------------------------------------------------
// K1: node linears, register-only MFMA. 64 nodes/block, 4 waves.
// ---------------------------------------------------------------------------
template <int OS>
__global__ __launch_bounds__(256) void k_node_mfma(
    const unsigned short* __restrict__ xsb, const unsigned short* __restrict__ xvpb,
    const float* __restrict__ attr,
    const unsigned short* __restrict__ wsb, const unsigned short* __restrict__ wvb,
    unsigned short* __restrict__ hsb, unsigned short* __restrict__ hvbb,
    float* __restrict__ scs, float* __restrict__ scv, int N)
{
    constexpr int NC1 = 64 + OS;
    constexpr int CT1 = NC1 / 16;
    __shared__ float attr_l[64];
    const int tid = threadIdx.x;
    const int n0 = blockIdx.x * 64;
    if (tid < 64) attr_l[tid] = (n0 + tid < N) ? attr[n0 + tid] : 0.f;
    __syncthreads();
    const int wv = tid >> 6, lane = tid & 63;
    const int mrow = lane & 15, kg = lane >> 4;

    {
        const int rbase = wv * 16;
        const int r = rbase + mrow;
        const int rc = min(n0 + r, N - 1);
        const bf16x8 a0 = *(const bf16x8*)(xsb + (size_t)rc * 64 + kg * 8);
        const bf16x8 a1 = *(const bf16x8*)(xsb + (size_t)rc * 64 + 32 + kg * 8);
        f32x4 acc[CT1];
        #pragma unroll
        for (int t = 0; t < CT1; t++) acc[t] = (f32x4){0.f, 0.f, 0.f, 0.f};
        #pragma unroll
        for (int t = 0; t < CT1; t++) {
            const int c = t * 16 + mrow;
            const bf16x8 b0 = *(const bf16x8*)(wsb + c * 64 + kg * 8);
            const bf16x8 b1 = *(const bf16x8*)(wsb + c * 64 + 32 + kg * 8);
            acc[t] = __builtin_amdgcn_mfma_f32_16x16x32_bf16(a0, b0, acc[t], 0, 0, 0);
            acc[t] = __builtin_amdgcn_mfma_f32_16x16x32_bf16(a1, b1, acc[t], 0, 0, 0);
        }
        #pragma unroll
        for (int t = 0; t < CT1; t++) {
            const int c = t * 16 + mrow;
            #pragma unroll
            for (int rg = 0; rg < 4; rg++) {
                const int row = rbase + kg * 4 + rg;
                const int n = n0 + row;
                if (n < N) {
                    const float v = acc[t][rg] * INV_SQRT64 * attr_l[row];
                    if (c < 64) hsb[(size_t)n * 64 + c] = f2bf(v);
                    else        scs[(size_t)n * OS + (c - 64)] = v;
                }
            }
        }
    }
    #pragma unroll
    for (int j = 0; j < 3; j++) {
        const int rbase = (wv * 3 + j) * 16;
        const int rv = rbase + mrow;
        const int ic = rv >> 6, nloc = rv & 63;
        const int nc = min(n0 + nloc, N - 1);
        const bf16x8 a = *(const bf16x8*)(xvpb + (size_t)nc * 96 + ic * 32 + kg * 8);
        f32x4 acc2[4];
        #pragma unroll
        for (int t = 0; t < 4; t++) acc2[t] = (f32x4){0.f, 0.f, 0.f, 0.f};
        #pragma unroll
        for (int t = 0; t < 4; t++) {
            const int c = t * 16 + mrow;
            const bf16x8 b = *(const bf16x8*)(wvb + c * 32 + kg * 8);
            acc2[t] = __builtin_amdgcn_mfma_f32_16x16x32_bf16(a, b, acc2[t], 0, 0, 0);
        }
        #pragma unroll
        for (int t = 0; t < 4; t++) {
            const int c = t * 16 + mrow;
            #pragma unroll
            for (int rg = 0; rg < 4; rg++) {
                const int rv2 = rbase + kg * 4 + rg;
                const int ic2 = rv2 >> 6, nl = rv2 & 63;
                const int n = n0 + nl;
                if (n < N) {
                    const float v = acc2[t][rg] * INV_SQRT32 * attr_l[nl];
                    if (c < 32) hvbb[(size_t)n * 96 + ic2 * 32 + c] = f2bf(v);
                    else        scv[(size_t)n * 96 + ic2 * 32 + (c - 32)] = v;
                }
            }
        }
    }
}

// ---------------------------------------------------------------------------
// K2a: edge MLP; packed per-lane stores (L3-resident wbuf at NQ=4).
// ---------------------------------------------------------------------------
__global__ __launch_bounds__(256) void k_edge_mlp(
    const unsigned short* __restrict__ esc_ordb, const int* __restrict__ base,
    const float* __restrict__ Wfc1, const unsigned short* __restrict__ wfb,
    unsigned* __restrict__ wbuf12, unsigned short* __restrict__ wbufB,
    int n0, int n1, int N, int E, int cap)
{
    __shared__ float esc_l[640];
    __shared__ float w1_l[640];
    __shared__ __align__(16) char hb[64 * 64 * 2];  // [row][k] bf16, swz ^((r&7)<<4)
    const int tid = threadIdx.x;
    const int lo = (n0 == 0) ? 0 : base[n0];
    const int hi = (n1 >= N) ? E : base[n1];
    const int p0 = lo + blockIdx.x * 64;
    if (p0 >= hi) return;

    for (int i = tid; i < 640; i += 256) w1_l[i] = Wfc1[i];
    {
        const size_t emax = (size_t)E * 10 - 1;
        for (int i = tid; i < 640; i += 256) {
            size_t idx = (size_t)p0 * 10 + i;
            esc_l[i] = bf2f(esc_ordb[idx > emax ? emax : idx]);
        }
    }
    __syncthreads();
    {
        const int r = tid >> 2, c0 = (tid & 3) << 4;
        float hval[16];
        #pragma unroll
        for (int c = 0; c < 16; c++) {
            float acc = 0.f;
            #pragma unroll
            for (int q = 0; q < 10; q++) acc += esc_l[r * 10 + q] * w1_l[q * 64 + c0 + c];
            acc *= INV_SQRT10;
            hval[c] = acc / (1.f + __expf(-acc));
        }
        unsigned pk[8];
        #pragma unroll
        for (int j = 0; j < 8; j++)
            pk[j] = (unsigned)f2bf(hval[2 * j]) | ((unsigned)f2bf(hval[2 * j + 1]) << 16);
        const int swz = (r & 7) << 4;
        const int b0 = (r << 7) + (c0 << 1);
        *(uint4*)(hb + (b0 ^ swz)) = make_uint4(pk[0], pk[1], pk[2], pk[3]);
        *(uint4*)(hb + ((b0 + 16) ^ swz)) = make_uint4(pk[4], pk[5], pk[6], pk[7]);
    }
    __syncthreads();
    const int wv = tid >> 6, lane = tid & 63;
    const int mrow = lane & 15, kgrp = lane >> 4;
    f32x4 acc[12];
    #pragma unroll
    for (int t = 0; t < 12; t++) acc[t] = (f32x4){0.f, 0.f, 0.f, 0.f};
    #pragma unroll
    for (int kc = 0; kc < 2; kc++) {
        const int r = wv * 16 + mrow;
        const int abyte = ((r << 7) + (kc << 6) + (kgrp << 4)) ^ ((r & 7) << 4);
        const bf16x8 afrag = *(const bf16x8*)(hb + abyte);
        #pragma unroll
        for (int t = 0; t < 12; t++) {
            const int c = t * 16 + mrow;
            const bf16x8 bfrag = *(const bf16x8*)(wfb + c * 64 + kc * 32 + kgrp * 8);
            acc[t] = __builtin_amdgcn_mfma_f32_16x16x32_bf16(afrag, bfrag, acc[t], 0, 0, 0);
        }
    }
    #pragma unroll
    for (int rg = 0; rg < 4; rg++) {
        const int rloc = wv * 16 + kgrp * 4 + rg;
        const int pos = p0 + rloc;
        if (pos < hi && (pos - lo) < cap) {
            uint4 pk12;
            pk12.x = (unsigned)f2bf(acc[0][rg] * INV_SQRT64) | ((unsigned)f2bf(acc[4][rg] * INV_SQRT64) << 16);
            pk12.y = (unsigned)f2bf(acc[1][rg] * INV_SQRT64) | ((unsigned)f2bf(acc[5][rg] * INV_SQRT64) << 16);
            pk12.z = (unsigned)f2bf(acc[2][rg] * INV_SQRT64) | ((unsigned)f2bf(acc[6][rg] * INV_SQRT64) << 16);
            pk12.w = (unsigned)f2bf(acc[3][rg] * INV_SQRT64) | ((unsigned)f2bf(acc[7][rg] * INV_SQRT64) << 16);
            ushort4 pkB;
            pkB.x = f2bf(acc[8][rg] * INV_SQRT64);
            pkB.y = f2bf(acc[9][rg] * INV_SQRT64);
            pkB.z = f2bf(acc[10][rg] * INV_SQRT64);
            pkB.w = f2bf(acc[11][rg] * INV_SQRT64);
            *(uint4*)(wbuf12 + (size_t)(pos - lo) * 64 + mrow * 4) = pk12;
            *(ushort4*)(wbufB + (size_t)(pos - lo) * 64 + mrow * 4) = pkB;
        }
    }
}

// ---------------------------------------------------------------------------
// K2b: aggregation only. wave-per-dst-node over CSR; writes deg-normalized
//   Msb (N x 96 bf16) and Mvb ((n*3+i) x 96 bf16).
//   wbuf column index is permuted: cidx = (lane&15)*4 + (lane>>4).
// ---------------------------------------------------------------------------
__global__ __launch_bounds__(256) void k_agg(
    const unsigned short* __restrict__ hsb, const unsigned short* __restrict__ hvbb,
    const int* __restrict__ src_ord, const float4* __restrict__ sh_ord,
    const int* __restrict__ base, const int* __restrict__ cnt,
    const unsigned* __restrict__ wbuf12, const unsigned short* __restrict__ wbufB,
    unsigned short* __restrict__ Msb, unsigned short* __restrict__ Mvb,
    int n0, int n1, int N, int E)
{
    const int wave = threadIdx.x >> 6, lane = threadIdx.x & 63;
    const int n = n0 + blockIdx.x * 4 + wave;
    if (n >= n1) return;
    const int lo = (n0 == 0) ? 0 : base[n0];
    const int cidx = (lane & 15) * 4 + (lane >> 4);

    float aS = 0.f, aSB = 0.f;
    float aV0 = 0.f, aV1 = 0.f, aV2 = 0.f;
    float aB0 = 0.f, aB1 = 0.f, aB2 = 0.f;
    const int b0 = base[n];
    const int c_ = cnt[n];
    const size_t wb = (size_t)(b0 - lo) * 64;
    int s_nx = (c_ > 0) ? src_ord[b0] : 0;
    for (int j = 0; j < c_; ++j) {
        const int s = s_nx;
        if (j + 1 < c_) s_nx = src_ord[b0 + j + 1];
        const unsigned p12 = wbuf12[wb + (size_t)j * 64 + cidx];
        const float w1 = bf2f((unsigned short)(p12 & 0xFFFF));
        const float w2 = bf2f((unsigned short)(p12 >> 16));
        const float wB = bf2f(wbufB[wb + (size_t)j * 64 + cidx]);
        const float gs = bf2f(hsb[(size_t)s * 64 + lane]);
        float gv0 = 0.f, gv1 = 0.f, gv2 = 0.f;
        if (lane < 32) {
            gv0 = bf2f(hvbb[(size_t)s * 96 + lane]);
            gv1 = bf2f(hvbb[(size_t)s * 96 + 32 + lane]);
            gv2 = bf2f(hvbb[(size_t)s * 96 + 64 + lane]);
        }
        const float4 s4 = sh_ord[b0 + j];
        const float gvdot = gv0 * s4.y + gv1 * s4.z + gv2 * s4.w;
        const float gvd = __shfl(gvdot, lane & 31);
        aS  += gs * s4.x * w1;
        aSB += gvd * INV_SQRT3 * wB;
        aV0 += gs * s4.y * w2;
        aV1 += gs * s4.z * w2;
        aV2 += gs * s4.w * w2;
        aB0 += gv0 * s4.x * wB;
        aB1 += gv1 * s4.x * wB;
        aB2 += gv2 * s4.x * wB;
    }
    const float invd = 1.f / (float)max(c_, 1);
    unsigned short* msp = Msb + (size_t)n * 96;
    unsigned short* mvp = Mvb + (size_t)n * 3 * 96;
    msp[lane] = f2bf(aS * invd);
    if (lane >= 32) msp[64 + (lane - 32)] = f2bf(aSB * invd);
    mvp[0 * 96 + lane] = f2bf(aV0 * invd);
    mvp[1 * 96 + lane] = f2bf(aV1 * invd);
    mvp[2 * 96 + lane] = f2bf(aV2 * invd);
    if (lane < 32) {
        mvp[0 * 96 + 64 + lane] = f2bf(aB0 * invd);
        mvp[1 * 96 + 64 + lane] = f2bf(aB1 * invd);
        mvp[2 * 96 + 64 + lane] = f2bf(aB2 * invd);
    }
}

// ---------------------------------------------------------------------------
// K3: node finalize as MFMA. 64 nodes/block, 4 waves.
// ---------------------------------------------------------------------------
template <int OS, bool FINAL>
__global__ __launch_bounds__(256) void k_node_out(
    const unsigned short* __restrict__ Msb, const unsigned short* __restrict__ Mvb,
    const float* __restrict__ attr,
    const float* __restrict__ scs, const float* __restrict__ scv,
    const unsigned short* __restrict__ wob, const unsigned short* __restrict__ wv2b,
    float* __restrict__ outF,
    unsigned short* __restrict__ outSb, unsigned short* __restrict__ outVb, int N)
{
    constexpr int CT1 = (OS + 16 + 15) / 16;   // 7 (OS=96) / 5 (OS=64)
    constexpr int TA = OS / 16;                // tile holding alpha col (mrow==0)
    __shared__ float attr_l[64];
    __shared__ float alpha_l[64];
    __shared__ float gate_l[64][32];
    const int tid = threadIdx.x;
    const int n0 = blockIdx.x * 64;
    if (tid < 64) attr_l[tid] = (n0 + tid < N) ? attr[n0 + tid] : 0.f;
    __syncthreads();
    const int wv = tid >> 6, lane = tid & 63;
    const int mrow = lane & 15, kg = lane >> 4;

    // ---- GEMM1
    const int rbase = wv * 16;
    const int rc = min(n0 + rbase + mrow, N - 1);
    f32x4 acc[CT1];
    #pragma unroll
    for (int t = 0; t < CT1; t++) acc[t] = (f32x4){0.f, 0.f, 0.f, 0.f};
    #pragma unroll
    for (int kc = 0; kc < 3; kc++) {
        const bf16x8 a = *(const bf16x8*)(Msb + (size_t)rc * 96 + kc * 32 + kg * 8);
        #pragma unroll
        for (int t = 0; t < CT1; t++) {
            const bf16x8 b = *(const bf16x8*)(wob + (size_t)(t * 16 + mrow) * 96 + kc * 32 + kg * 8);
            acc[t] = __builtin_amdgcn_mfma_f32_16x16x32_bf16(a, b, acc[t], 0, 0, 0);
        }
    }
    if (mrow == 0) {
        #pragma unroll
        for (int rg = 0; rg < 4; rg++) {
            const int row = rbase + kg * 4 + rg;
            alpha_l[row] = acc[TA][rg] * INV_SQRT96 * attr_l[row];
        }
    }
    __syncthreads();
    // ---- epilogue 1
    #pragma unroll
    for (int t = 0; t < CT1; t++) {
        const int c = t * 16 + mrow;
        if (c < OS) {
            #pragma unroll
            for (int rg = 0; rg < 4; rg++) {
                const int row = rbase + kg * 4 + rg;
                const int n = n0 + row;
                if (n < N) {
                    const float os = acc[t][rg] * INV_SQRT96 * attr_l[row];
                    const float s = scs[(size_t)n * OS + c] + alpha_l[row] * os;
                    if (FINAL) {
                        outF[(size_t)n * 160 + c] = s;
                    } else {
                        if (c < 64) outSb[(size_t)n * 64 + c] = f2bf(s / (1.f + __expf(-s)));
                        else        gate_l[row][c - 64] = 1.f / (1.f + __expf(-s));
                    }
                }
            }
        }
    }
    __syncthreads();
    // ---- GEMM2: rows rv = nloc*3+i (192), wave handles 3 row-tiles
    #pragma unroll
    for (int j = 0; j < 3; j++) {
        const int rb2 = (wv * 3 + j) * 16;
        const int rv = rb2 + mrow;
        const int nl = rv / 3, ii = rv - nl * 3;
        const int nc2 = min(n0 + nl, N - 1);
        f32x4 acc2[2];
        acc2[0] = (f32x4){0.f, 0.f, 0.f, 0.f};
        acc2[1] = (f32x4){0.f, 0.f, 0.f, 0.f};
        #pragma unroll
        for (int kc = 0; kc < 3; kc++) {
            const bf16x8 a = *(const bf16x8*)(Mvb + ((size_t)nc2 * 3 + ii) * 96 + kc * 32 + kg * 8);
            #pragma unroll
            for (int t = 0; t < 2; t++) {
                const bf16x8 b = *(const bf16x8*)(wv2b + (size_t)(t * 16 + mrow) * 96 + kc * 32 + kg * 8);
                acc2[t] = __builtin_amdgcn_mfma_f32_16x16x32_bf16(a, b, acc2[t], 0, 0, 0);
            }
        }
        #pragma unroll
        for (int t = 0; t < 2; t++) {
            const int k = t * 16 + mrow;
            #pragma unroll
            for (int rg = 0; rg < 4; rg++) {
                const int rv2 = rb2 + kg * 4 + rg;
                const int nl2 = rv2 / 3, i2 = rv2 - nl2 * 3;
                const int n = n0 + nl2;
                if (n < N) {
                    const float ov = acc2[t][rg] * INV_SQRT96 * attr_l[nl2];
                    const float v = scv[(size_t)n * 96 + i2 * 32 + k] + alpha_l[nl2] * ov;
                    if (FINAL) outF[(size_t)n * 160 + 64 + k * 3 + i2] = v;
                    else       outVb[(size_t)n * 96 + i2 * 32 + k] = f2bf(v * gate_l[nl2][k]);
                }
            }
        }
    }
}

// ---------------------------------------------------------------------------
extern "C" void kernel_launch(void* const* d_in, const int* in_sizes, int n_in,
                              void* d_out, int out_size, void* d_ws, size_t ws_size,
                              hipStream_t stream)
{
    const float* node_s = (const float*)d_in[0];
    const float* node_v = (const float*)d_in[1];
    const float* attr   = (const float*)d_in[2];
    const int*   esrc   = (const int*)d_in[3];
    const int*   edst   = (const int*)d_in[4];
    const float* esh    = (const float*)d_in[5];
    const float* esc    = (const float*)d_in[6];
    const float* W[18];
    for (int i = 0; i < 18; i++) W[i] = (const float*)d_in[7 + i];
    // per layer: 0 sc_s, 1 sc_v, 2 lin1_s, 3 lin1_v, 4 fc1, 5 fc2, 6 lin2_s, 7 lin2_v, 8 alpha

    const int N = in_sizes[0] / 64;
    const int E = in_sizes[3];
    const int NB = (N + 255) / 256;

    char* p = (char*)d_ws;
    unsigned short* xsb  = (unsigned short*)p; p += (size_t)N * 64 * 2;
    unsigned short* xvpb = (unsigned short*)p; p += (size_t)N * 96 * 2;
    unsigned short* hsb  = (unsigned short*)p; p += (size_t)N * 64 * 2;
    unsigned short* hvbb = (unsigned short*)p; p += (size_t)N * 96 * 2;
    unsigned short* Msb  = (unsigned short*)p; p += (size_t)N * 96 * 2;
    unsigned short* Mvb  = (unsigned short*)p; p += (size_t)N * 288 * 2;
    float* scs = (float*)p; p += (size_t)N * 96 * 4;
    float* scv = (float*)p; p += (size_t)N * 96 * 4;
    unsigned short* wsb1 = (unsigned short*)p; p += 160 * 64 * 2;
    unsigned short* wsb2 = (unsigned short*)p; p += 128 * 64 * 2;
    unsigned short* wvb1 = (unsigned short*)p; p += 64 * 32 * 2;
    unsigned short* wvb2 = (unsigned short*)p; p += 64 * 32 * 2;
    unsigned short* wfb1 = (unsigned short*)p; p += 192 * 64 * 2;
    unsigned short* wfb2 = (unsigned short*)p; p += 192 * 64 * 2;
    unsigned short* wob1 = (unsigned short*)p; p += 112 * 96 * 2;
    unsigned short* wob2 = (unsigned short*)p; p += 80 * 96 * 2;
    unsigned short* wv2b1 = (unsigned short*)p; p += 32 * 96 * 2;
    unsigned short* wv2b2 = (unsigned short*)p; p += 32 * 96 * 2;
    int* cnt    = (int*)p; p += (size_t)N * 4;
    int* cursor = (int*)p; p += (size_t)N * 4;
    int* basei  = (int*)p; p += (size_t)N * 4;
    int* partial = (int*)p; p += (size_t)NB * 4;
    p = (char*)(((size_t)p + 255) & ~(size_t)255);
    int* src_ord = (int*)p; p += (size_t)E * 4;
    p = (char*)(((size_t)p + 15) & ~(size_t)15);
    float4* sh_ord = (float4*)p; p += (size_t)E * 16;
    unsigned short* esc_ordb = (unsigned short*)p; p += (size_t)E * 20;
    p = (char*)(((size_t)p + 255) & ~(size_t)255);

    // NQ=4: wbuf quarter (~38 MB) stays L3-resident, no HBM round-trip
    const int NQ = 4;
    const size_t cap = ((size_t)E / NQ) * 9 / 8 + 256;
    unsigned* wbuf12      = (unsigned*)p;       p += cap * 256;
    unsigned short* wbufB = (unsigned short*)p; p += cap * 128;

    const int nb  = (N + 63) / 64;
    const int ebk = (E + 255) / 256;
    const int Q   = (N + NQ - 1) / NQ;
    const int qb  = (Q + 3) / 4;
    const int emb = (int)((cap + 63) / 64);

    // ---- prep + CSR build
    hipMemsetAsync(cnt, 0, (size_t)2 * N * sizeof(int), stream);  // cnt + cursor
    k_prep_nodes<<<2048, 256, 0, stream>>>(node_s, node_v, edst, xsb, xvpb, cnt, N, E);
    k_prep_w<96><<<32, 256, 0, stream>>>(W[2], W[0], W[3], W[1], W[5], W[6], W[7], W[8],
                                         wsb1, wvb1, wfb1, wob1, wv2b1);
    k_prep_w<64><<<32, 256, 0, stream>>>(W[11], W[9], W[12], W[10], W[14], W[15], W[16], W[17],
                                         wsb2, wvb2, wfb2, wob2, wv2b2);
    k_scan1<<<NB, 256, 0, stream>>>(cnt, partial, N);
    k_scan2<<<1, 1024, 0, stream>>>(partial, NB);
    k_scan3<<<NB, 256, 0, stream>>>(cnt, partial, basei, N);
    k_scatter<<<ebk, 256, 0, stream>>>(esrc, edst, esh, esc, basei, cursor,
                                       src_ord, sh_ord, esc_ordb, E);

    // ---- layer 1
    k_node_mfma<96><<<nb, 256, 0, stream>>>(xsb, xvpb, attr, wsb1, wvb1,
                                            hsb, hvbb, scs, scv, N);
    for (int q = 0; q < NQ; q++) {
        const int n0 = q * Q, n1 = min(N, (q + 1) * Q);
        if (n0 >= n1) break;
        k_edge_mlp<<<emb, 256, 0, stream>>>(esc_ordb, basei, W[4], wfb1,
                                            wbuf12, wbufB, n0, n1, N, E, (int)cap);
        k_agg<<<qb, 256, 0, stream>>>(hsb, hvbb, src_ord, sh_ord, basei, cnt,
                                      wbuf12, wbufB, Msb, Mvb, n0, n1, N, E);
    }
    k_node_out<96, false><<<nb, 256, 0, stream>>>(Msb, Mvb, attr, scs, scv,
                                                  wob1, wv2b1,
                                                  nullptr, xsb, xvpb, N);
    // ---- layer 2
    k_node_mfma<64><<<nb, 256, 0, stream>>>(xsb, xvpb, attr, wsb2, wvb2,
                                            hsb, hvbb, scs, scv, N);
    for (int q = 0; q < NQ; q++) {
        const int n0 = q * Q, n1 = min(N, (q + 1) * Q);
        if (n0 >= n1) break;
        k_edge_mlp<<<emb, 256, 0, stream>>>(esc_ordb, basei, W[13], wfb2,
                                            wbuf12, wbufB, n0, n1, N, E, (int)cap);
        k_agg<<<qb, 256, 0, stream>>>(hsb, hvbb, src_ord, sh_ord, basei, cnt,
                                      wbuf12, wbufB, Msb, Mvb, n0, n1, N, E);
    }
    k_node_out<64, true><<<nb, 256, 0, stream>>>(Msb, Mvb, attr, scs, scv,
                                                 wob2, wv2b2,
                                                 (float*)d_out, nullptr, nullptr, N);
}

// Round 11
// 545.614 us; speedup vs baseline: 2.4638x; 1.2120x over previous
//
#include <hip/hip_runtime.h>
#include <hip/hip_bf16.h>

#define INV_SQRT10 0.31622776601683794f
#define INV_SQRT64 0.125f
#define INV_SQRT32 0.17677669529663687f
#define INV_SQRT96 0.10206207261596575f
#define INV_SQRT3  0.5773502691896258f

typedef __attribute__((ext_vector_type(4))) float f32x4;
typedef __attribute__((ext_vector_type(8))) short bf16x8;

__device__ __forceinline__ unsigned short f2bf(float x) {
    union { float f; unsigned u; } v; v.f = x;
    unsigned r = v.u + 0x7FFF + ((v.u >> 16) & 1);
    return (unsigned short)(r >> 16);
}
__device__ __forceinline__ float bf2f(unsigned short u) {
    union { unsigned u; float f; } v; v.u = ((unsigned)u) << 16;
    return v.f;
}

// ---------------------------------------------------------------------------
// prep: node features -> bf16 (xs N x 64; xvp plane-major) + degree count
// ---------------------------------------------------------------------------
__global__ __launch_bounds__(256) void k_prep_nodes(
    const float* __restrict__ ns, const float* __restrict__ nv,
    const int* __restrict__ dst,
    unsigned short* __restrict__ xsb, unsigned short* __restrict__ xvpb,
    int* __restrict__ cnt, int N, int E)
{
    const int gid = blockIdx.x * 256 + threadIdx.x, gs = gridDim.x * 256;
    for (int i = gid; i < N * 64; i += gs) xsb[i] = f2bf(ns[i]);
    for (int i = gid; i < N * 96; i += gs) {
        const int n = i / 96, rem = i - n * 96;
        const int ic = rem >> 5, u = rem & 31;
        xvpb[i] = f2bf(nv[(size_t)n * 96 + u * 3 + ic]);
    }
    for (int i = gid; i < E; i += gs) atomicAdd(&cnt[dst[i]], 1);
}

// ---------------------------------------------------------------------------
// prep: weights -> bf16 panels.
// ---------------------------------------------------------------------------
template <int OS>
__global__ __launch_bounds__(256) void k_prep_w(
    const float* __restrict__ Wl1s, const float* __restrict__ Wscs,
    const float* __restrict__ Wl1v, const float* __restrict__ Wscv,
    const float* __restrict__ Wfc2,
    const float* __restrict__ W2s, const float* __restrict__ W2v,
    const float* __restrict__ Wa,
    unsigned short* __restrict__ wsb, unsigned short* __restrict__ wvb,
    unsigned short* __restrict__ wfb,
    unsigned short* __restrict__ wob, unsigned short* __restrict__ wv2b)
{
    constexpr int NC1 = 64 + OS;
    constexpr int PC1 = ((OS + 16 + 15) / 16) * 16;   // 112 (OS=96) / 80 (OS=64)
    const int gid = blockIdx.x * 256 + threadIdx.x, gs = gridDim.x * 256;
    for (int i = gid; i < NC1 * 64; i += gs) {
        const int c = i >> 6, k = i & 63;
        const float v = (c < 64) ? Wl1s[k * 64 + c] : Wscs[k * OS + (c - 64)];
        wsb[i] = f2bf(v);
    }
    for (int i = gid; i < 64 * 32; i += gs) {
        const int c = i >> 5, u = i & 31;
        const float v = (c < 32) ? Wl1v[u * 32 + c] : Wscv[u * 32 + (c - 32)];
        wvb[i] = f2bf(v);
    }
    for (int i = gid; i < 192 * 64; i += gs) {
        const int c = i >> 6, k = i & 63;
        wfb[i] = f2bf(Wfc2[k * 192 + c]);
    }
    for (int i = gid; i < PC1 * 96; i += gs) {
        const int c = i / 96, u = i - c * 96;
        float v = 0.f;
        if (c < OS) v = W2s[u * OS + c];
        else if (c == OS) v = Wa[u];
        wob[i] = f2bf(v);
    }
    for (int i = gid; i < 32 * 96; i += gs) {
        const int c = i / 96, u = i - c * 96;
        wv2b[i] = f2bf(W2v[u * 32 + c]);
    }
}

// ---------------------------------------------------------------------------
// Hierarchical exclusive scan of cnt -> base.
// ---------------------------------------------------------------------------
__global__ __launch_bounds__(256) void k_scan1(const int* __restrict__ cnt,
                                               int* __restrict__ partial, int N)
{
    __shared__ int lds[256];
    const int t = threadIdx.x, i = blockIdx.x * 256 + t;
    int v = (i < N) ? cnt[i] : 0;
    lds[t] = v;
    __syncthreads();
    for (int off = 128; off > 0; off >>= 1) {
        if (t < off) lds[t] += lds[t + off];
        __syncthreads();
    }
    if (t == 0) partial[blockIdx.x] = lds[0];
}

__global__ __launch_bounds__(1024) void k_scan2(int* __restrict__ partial, int NB)
{
    __shared__ int lds[1024];
    const int t = threadIdx.x;
    int v = (t < NB) ? partial[t] : 0;
    lds[t] = v;
    __syncthreads();
    for (int off = 1; off < 1024; off <<= 1) {
        int w = (t >= off) ? lds[t - off] : 0;
        __syncthreads();
        lds[t] += w;
        __syncthreads();
    }
    if (t < NB) partial[t] = lds[t] - v;   // exclusive
}

__global__ __launch_bounds__(256) void k_scan3(const int* __restrict__ cnt,
                                               const int* __restrict__ partial,
                                               int* __restrict__ base, int N)
{
    __shared__ int lds[256];
    const int t = threadIdx.x, i = blockIdx.x * 256 + t;
    int v = (i < N) ? cnt[i] : 0;
    lds[t] = v;
    __syncthreads();
    for (int off = 1; off < 256; off <<= 1) {
        int w = (t >= off) ? lds[t - off] : 0;
        __syncthreads();
        lds[t] += w;
        __syncthreads();
    }
    if (i < N) base[i] = partial[blockIdx.x] + lds[t] - v;
}

// ---------------------------------------------------------------------------
// order: scatter only the permutation (4B scattered writes).
// ---------------------------------------------------------------------------
__global__ __launch_bounds__(256) void k_order(
    const int* __restrict__ dst, const int* __restrict__ base,
    int* __restrict__ cursor, int* __restrict__ order, int E)
{
    int i = blockIdx.x * 256 + threadIdx.x;
    if (i < E) {
        const int d = dst[i];
        order[base[d] + atomicAdd(&cursor[d], 1)] = i;
    }
}

// ---------------------------------------------------------------------------
// gather: CSR-ordered src / sh (f32) / esc (bf16) with COALESCED writes.
// ---------------------------------------------------------------------------
__global__ __launch_bounds__(256) void k_gather(
    const int* __restrict__ order,
    const int* __restrict__ src, const float* __restrict__ sh,
    const float* __restrict__ esc,
    int* __restrict__ src_ord, float4* __restrict__ sh_ord,
    unsigned short* __restrict__ esc_ordb, int E)
{
    int pos = blockIdx.x * 256 + threadIdx.x;
    if (pos < E) {
        const int e = order[pos];
        src_ord[pos] = src[e];
        sh_ord[pos] = ((const float4*)sh)[e];
        const float* ep = esc + (size_t)e * 10;
        unsigned short* eo = esc_ordb + (size_t)pos * 10;
        #pragma unroll
        for (int q = 0; q < 10; q++) eo[q] = f2bf(ep[q]);
    }
}

// ---------------------------------------------------------------------------
// K1: node linears, register-only MFMA. 64 nodes/block, 4 waves.
//   outputs: hs/hv bf16; scs/scv bf16.
// ---------------------------------------------------------------------------
template <int OS>
__global__ __launch_bounds__(256) void k_node_mfma(
    const unsigned short* __restrict__ xsb, const unsigned short* __restrict__ xvpb,
    const float* __restrict__ attr,
    const unsigned short* __restrict__ wsb, const unsigned short* __restrict__ wvb,
    unsigned short* __restrict__ hsb, unsigned short* __restrict__ hvbb,
    unsigned short* __restrict__ scs, unsigned short* __restrict__ scv, int N)
{
    constexpr int NC1 = 64 + OS;
    constexpr int CT1 = NC1 / 16;
    __shared__ float attr_l[64];
    const int tid = threadIdx.x;
    const int n0 = blockIdx.x * 64;
    if (tid < 64) attr_l[tid] = (n0 + tid < N) ? attr[n0 + tid] : 0.f;
    __syncthreads();
    const int wv = tid >> 6, lane = tid & 63;
    const int mrow = lane & 15, kg = lane >> 4;

    {
        const int rbase = wv * 16;
        const int r = rbase + mrow;
        const int rc = min(n0 + r, N - 1);
        const bf16x8 a0 = *(const bf16x8*)(xsb + (size_t)rc * 64 + kg * 8);
        const bf16x8 a1 = *(const bf16x8*)(xsb + (size_t)rc * 64 + 32 + kg * 8);
        f32x4 acc[CT1];
        #pragma unroll
        for (int t = 0; t < CT1; t++) acc[t] = (f32x4){0.f, 0.f, 0.f, 0.f};
        #pragma unroll
        for (int t = 0; t < CT1; t++) {
            const int c = t * 16 + mrow;
            const bf16x8 b0 = *(const bf16x8*)(wsb + c * 64 + kg * 8);
            const bf16x8 b1 = *(const bf16x8*)(wsb + c * 64 + 32 + kg * 8);
            acc[t] = __builtin_amdgcn_mfma_f32_16x16x32_bf16(a0, b0, acc[t], 0, 0, 0);
            acc[t] = __builtin_amdgcn_mfma_f32_16x16x32_bf16(a1, b1, acc[t], 0, 0, 0);
        }
        #pragma unroll
        for (int t = 0; t < CT1; t++) {
            const int c = t * 16 + mrow;
            #pragma unroll
            for (int rg = 0; rg < 4; rg++) {
                const int row = rbase + kg * 4 + rg;
                const int n = n0 + row;
                if (n < N) {
                    const float v = acc[t][rg] * INV_SQRT64 * attr_l[row];
                    if (c < 64) hsb[(size_t)n * 64 + c] = f2bf(v);
                    else        scs[(size_t)n * OS + (c - 64)] = f2bf(v);
                }
            }
        }
    }
    #pragma unroll
    for (int j = 0; j < 3; j++) {
        const int rbase = (wv * 3 + j) * 16;
        const int rv = rbase + mrow;
        const int ic = rv >> 6, nloc = rv & 63;
        const int nc = min(n0 + nloc, N - 1);
        const bf16x8 a = *(const bf16x8*)(xvpb + (size_t)nc * 96 + ic * 32 + kg * 8);
        f32x4 acc2[4];
        #pragma unroll
        for (int t = 0; t < 4; t++) acc2[t] = (f32x4){0.f, 0.f, 0.f, 0.f};
        #pragma unroll
        for (int t = 0; t < 4; t++) {
            const int c = t * 16 + mrow;
            const bf16x8 b = *(const bf16x8*)(wvb + c * 32 + kg * 8);
            acc2[t] = __builtin_amdgcn_mfma_f32_16x16x32_bf16(a, b, acc2[t], 0, 0, 0);
        }
        #pragma unroll
        for (int t = 0; t < 4; t++) {
            const int c = t * 16 + mrow;
            #pragma unroll
            for (int rg = 0; rg < 4; rg++) {
                const int rv2 = rbase + kg * 4 + rg;
                const int ic2 = rv2 >> 6, nl = rv2 & 63;
                const int n = n0 + nl;
                if (n < N) {
                    const float v = acc2[t][rg] * INV_SQRT32 * attr_l[nl];
                    if (c < 32) hvbb[(size_t)n * 96 + ic2 * 32 + c] = f2bf(v);
                    else        scv[(size_t)n * 96 + ic2 * 32 + (c - 32)] = f2bf(v);
                }
            }
        }
    }
}

// ---------------------------------------------------------------------------
// K2a: edge MLP; packed per-lane stores.
// ---------------------------------------------------------------------------
__global__ __launch_bounds__(256) void k_edge_mlp(
    const unsigned short* __restrict__ esc_ordb, const int* __restrict__ base,
    const float* __restrict__ Wfc1, const unsigned short* __restrict__ wfb,
    unsigned* __restrict__ wbuf12, unsigned short* __restrict__ wbufB,
    int n0, int n1, int N, int E, int cap)
{
    __shared__ float esc_l[640];
    __shared__ float w1_l[640];
    __shared__ __align__(16) char hb[64 * 64 * 2];  // [row][k] bf16, swz ^((r&7)<<4)
    const int tid = threadIdx.x;
    const int lo = (n0 == 0) ? 0 : base[n0];
    const int hi = (n1 >= N) ? E : base[n1];
    const int p0 = lo + blockIdx.x * 64;
    if (p0 >= hi) return;

    for (int i = tid; i < 640; i += 256) w1_l[i] = Wfc1[i];
    {
        const size_t emax = (size_t)E * 10 - 1;
        for (int i = tid; i < 640; i += 256) {
            size_t idx = (size_t)p0 * 10 + i;
            esc_l[i] = bf2f(esc_ordb[idx > emax ? emax : idx]);
        }
    }
    __syncthreads();
    {
        const int r = tid >> 2, c0 = (tid & 3) << 4;
        float hval[16];
        #pragma unroll
        for (int c = 0; c < 16; c++) {
            float acc = 0.f;
            #pragma unroll
            for (int q = 0; q < 10; q++) acc += esc_l[r * 10 + q] * w1_l[q * 64 + c0 + c];
            acc *= INV_SQRT10;
            hval[c] = acc / (1.f + __expf(-acc));
        }
        unsigned pk[8];
        #pragma unroll
        for (int j = 0; j < 8; j++)
            pk[j] = (unsigned)f2bf(hval[2 * j]) | ((unsigned)f2bf(hval[2 * j + 1]) << 16);
        const int swz = (r & 7) << 4;
        const int b0 = (r << 7) + (c0 << 1);
        *(uint4*)(hb + (b0 ^ swz)) = make_uint4(pk[0], pk[1], pk[2], pk[3]);
        *(uint4*)(hb + ((b0 + 16) ^ swz)) = make_uint4(pk[4], pk[5], pk[6], pk[7]);
    }
    __syncthreads();
    const int wv = tid >> 6, lane = tid & 63;
    const int mrow = lane & 15, kgrp = lane >> 4;
    f32x4 acc[12];
    #pragma unroll
    for (int t = 0; t < 12; t++) acc[t] = (f32x4){0.f, 0.f, 0.f, 0.f};
    #pragma unroll
    for (int kc = 0; kc < 2; kc++) {
        const int r = wv * 16 + mrow;
        const int abyte = ((r << 7) + (kc << 6) + (kgrp << 4)) ^ ((r & 7) << 4);
        const bf16x8 afrag = *(const bf16x8*)(hb + abyte);
        #pragma unroll
        for (int t = 0; t < 12; t++) {
            const int c = t * 16 + mrow;
            const bf16x8 bfrag = *(const bf16x8*)(wfb + c * 64 + kc * 32 + kgrp * 8);
            acc[t] = __builtin_amdgcn_mfma_f32_16x16x32_bf16(afrag, bfrag, acc[t], 0, 0, 0);
        }
    }
    #pragma unroll
    for (int rg = 0; rg < 4; rg++) {
        const int rloc = wv * 16 + kgrp * 4 + rg;
        const int pos = p0 + rloc;
        if (pos < hi && (pos - lo) < cap) {
            uint4 pk12;
            pk12.x = (unsigned)f2bf(acc[0][rg] * INV_SQRT64) | ((unsigned)f2bf(acc[4][rg] * INV_SQRT64) << 16);
            pk12.y = (unsigned)f2bf(acc[1][rg] * INV_SQRT64) | ((unsigned)f2bf(acc[5][rg] * INV_SQRT64) << 16);
            pk12.z = (unsigned)f2bf(acc[2][rg] * INV_SQRT64) | ((unsigned)f2bf(acc[6][rg] * INV_SQRT64) << 16);
            pk12.w = (unsigned)f2bf(acc[3][rg] * INV_SQRT64) | ((unsigned)f2bf(acc[7][rg] * INV_SQRT64) << 16);
            ushort4 pkB;
            pkB.x = f2bf(acc[8][rg] * INV_SQRT64);
            pkB.y = f2bf(acc[9][rg] * INV_SQRT64);
            pkB.z = f2bf(acc[10][rg] * INV_SQRT64);
            pkB.w = f2bf(acc[11][rg] * INV_SQRT64);
            *(uint4*)(wbuf12 + (size_t)(pos - lo) * 64 + mrow * 4) = pk12;
            *(ushort4*)(wbufB + (size_t)(pos - lo) * 64 + mrow * 4) = pkB;
        }
    }
}

// ---------------------------------------------------------------------------
// K2b: aggregation only. wave-per-dst-node over CSR; writes deg-normalized
//   Msb (N x 96 bf16) and Mvb ((n*3+i) x 96 bf16).
//   wbuf column index is permuted: cidx = (lane&15)*4 + (lane>>4).
// ---------------------------------------------------------------------------
__global__ __launch_bounds__(256) void k_agg(
    const unsigned short* __restrict__ hsb, const unsigned short* __restrict__ hvbb,
    const int* __restrict__ src_ord, const float4* __restrict__ sh_ord,
    const int* __restrict__ base, const int* __restrict__ cnt,
    const unsigned* __restrict__ wbuf12, const unsigned short* __restrict__ wbufB,
    unsigned short* __restrict__ Msb, unsigned short* __restrict__ Mvb,
    int n0, int n1, int N, int E)
{
    const int wave = threadIdx.x >> 6, lane = threadIdx.x & 63;
    const int n = n0 + blockIdx.x * 4 + wave;
    if (n >= n1) return;
    const int lo = (n0 == 0) ? 0 : base[n0];
    const int cidx = (lane & 15) * 4 + (lane >> 4);

    float aS = 0.f, aSB = 0.f;
    float aV0 = 0.f, aV1 = 0.f, aV2 = 0.f;
    float aB0 = 0.f, aB1 = 0.f, aB2 = 0.f;
    const int b0 = base[n];
    const int c_ = cnt[n];
    const size_t wb = (size_t)(b0 - lo) * 64;
    int s_nx = (c_ > 0) ? src_ord[b0] : 0;
    for (int j = 0; j < c_; ++j) {
        const int s = s_nx;
        if (j + 1 < c_) s_nx = src_ord[b0 + j + 1];
        const unsigned p12 = wbuf12[wb + (size_t)j * 64 + cidx];
        const float w1 = bf2f((unsigned short)(p12 & 0xFFFF));
        const float w2 = bf2f((unsigned short)(p12 >> 16));
        const float wB = bf2f(wbufB[wb + (size_t)j * 64 + cidx]);
        const float gs = bf2f(hsb[(size_t)s * 64 + lane]);
        float gv0 = 0.f, gv1 = 0.f, gv2 = 0.f;
        if (lane < 32) {
            gv0 = bf2f(hvbb[(size_t)s * 96 + lane]);
            gv1 = bf2f(hvbb[(size_t)s * 96 + 32 + lane]);
            gv2 = bf2f(hvbb[(size_t)s * 96 + 64 + lane]);
        }
        const float4 s4 = sh_ord[b0 + j];
        const float gvdot = gv0 * s4.y + gv1 * s4.z + gv2 * s4.w;
        const float gvd = __shfl(gvdot, lane & 31);
        aS  += gs * s4.x * w1;
        aSB += gvd * INV_SQRT3 * wB;
        aV0 += gs * s4.y * w2;
        aV1 += gs * s4.z * w2;
        aV2 += gs * s4.w * w2;
        aB0 += gv0 * s4.x * wB;
        aB1 += gv1 * s4.x * wB;
        aB2 += gv2 * s4.x * wB;
    }
    const float invd = 1.f / (float)max(c_, 1);
    unsigned short* msp = Msb + (size_t)n * 96;
    unsigned short* mvp = Mvb + (size_t)n * 3 * 96;
    msp[lane] = f2bf(aS * invd);
    if (lane >= 32) msp[64 + (lane - 32)] = f2bf(aSB * invd);
    mvp[0 * 96 + lane] = f2bf(aV0 * invd);
    mvp[1 * 96 + lane] = f2bf(aV1 * invd);
    mvp[2 * 96 + lane] = f2bf(aV2 * invd);
    if (lane < 32) {
        mvp[0 * 96 + 64 + lane] = f2bf(aB0 * invd);
        mvp[1 * 96 + 64 + lane] = f2bf(aB1 * invd);
        mvp[2 * 96 + 64 + lane] = f2bf(aB2 * invd);
    }
}

// ---------------------------------------------------------------------------
// K3: node finalize as MFMA. 64 nodes/block, 4 waves. scs/scv bf16.
// ---------------------------------------------------------------------------
template <int OS, bool FINAL>
__global__ __launch_bounds__(256) void k_node_out(
    const unsigned short* __restrict__ Msb, const unsigned short* __restrict__ Mvb,
    const float* __restrict__ attr,
    const unsigned short* __restrict__ scs, const unsigned short* __restrict__ scv,
    const unsigned short* __restrict__ wob, const unsigned short* __restrict__ wv2b,
    float* __restrict__ outF,
    unsigned short* __restrict__ outSb, unsigned short* __restrict__ outVb, int N)
{
    constexpr int CT1 = (OS + 16 + 15) / 16;   // 7 (OS=96) / 5 (OS=64)
    constexpr int TA = OS / 16;                // tile holding alpha col (mrow==0)
    __shared__ float attr_l[64];
    __shared__ float alpha_l[64];
    __shared__ float gate_l[64][32];
    const int tid = threadIdx.x;
    const int n0 = blockIdx.x * 64;
    if (tid < 64) attr_l[tid] = (n0 + tid < N) ? attr[n0 + tid] : 0.f;
    __syncthreads();
    const int wv = tid >> 6, lane = tid & 63;
    const int mrow = lane & 15, kg = lane >> 4;

    // ---- GEMM1
    const int rbase = wv * 16;
    const int rc = min(n0 + rbase + mrow, N - 1);
    f32x4 acc[CT1];
    #pragma unroll
    for (int t = 0; t < CT1; t++) acc[t] = (f32x4){0.f, 0.f, 0.f, 0.f};
    #pragma unroll
    for (int kc = 0; kc < 3; kc++) {
        const bf16x8 a = *(const bf16x8*)(Msb + (size_t)rc * 96 + kc * 32 + kg * 8);
        #pragma unroll
        for (int t = 0; t < CT1; t++) {
            const bf16x8 b = *(const bf16x8*)(wob + (size_t)(t * 16 + mrow) * 96 + kc * 32 + kg * 8);
            acc[t] = __builtin_amdgcn_mfma_f32_16x16x32_bf16(a, b, acc[t], 0, 0, 0);
        }
    }
    if (mrow == 0) {
        #pragma unroll
        for (int rg = 0; rg < 4; rg++) {
            const int row = rbase + kg * 4 + rg;
            alpha_l[row] = acc[TA][rg] * INV_SQRT96 * attr_l[row];
        }
    }
    __syncthreads();
    // ---- epilogue 1
    #pragma unroll
    for (int t = 0; t < CT1; t++) {
        const int c = t * 16 + mrow;
        if (c < OS) {
            #pragma unroll
            for (int rg = 0; rg < 4; rg++) {
                const int row = rbase + kg * 4 + rg;
                const int n = n0 + row;
                if (n < N) {
                    const float os = acc[t][rg] * INV_SQRT96 * attr_l[row];
                    const float s = bf2f(scs[(size_t)n * OS + c]) + alpha_l[row] * os;
                    if (FINAL) {
                        outF[(size_t)n * 160 + c] = s;
                    } else {
                        if (c < 64) outSb[(size_t)n * 64 + c] = f2bf(s / (1.f + __expf(-s)));
                        else        gate_l[row][c - 64] = 1.f / (1.f + __expf(-s));
                    }
                }
            }
        }
    }
    __syncthreads();
    // ---- GEMM2: rows rv = nloc*3+i (192), wave handles 3 row-tiles
    #pragma unroll
    for (int j = 0; j < 3; j++) {
        const int rb2 = (wv * 3 + j) * 16;
        const int rv = rb2 + mrow;
        const int nl = rv / 3, ii = rv - nl * 3;
        const int nc2 = min(n0 + nl, N - 1);
        f32x4 acc2[2];
        acc2[0] = (f32x4){0.f, 0.f, 0.f, 0.f};
        acc2[1] = (f32x4){0.f, 0.f, 0.f, 0.f};
        #pragma unroll
        for (int kc = 0; kc < 3; kc++) {
            const bf16x8 a = *(const bf16x8*)(Mvb + ((size_t)nc2 * 3 + ii) * 96 + kc * 32 + kg * 8);
            #pragma unroll
            for (int t = 0; t < 2; t++) {
                const bf16x8 b = *(const bf16x8*)(wv2b + (size_t)(t * 16 + mrow) * 96 + kc * 32 + kg * 8);
                acc2[t] = __builtin_amdgcn_mfma_f32_16x16x32_bf16(a, b, acc2[t], 0, 0, 0);
            }
        }
        #pragma unroll
        for (int t = 0; t < 2; t++) {
            const int k = t * 16 + mrow;
            #pragma unroll
            for (int rg = 0; rg < 4; rg++) {
                const int rv2 = rb2 + kg * 4 + rg;
                const int nl2 = rv2 / 3, i2 = rv2 - nl2 * 3;
                const int n = n0 + nl2;
                if (n < N) {
                    const float ov = acc2[t][rg] * INV_SQRT96 * attr_l[nl2];
                    const float v = bf2f(scv[(size_t)n * 96 + i2 * 32 + k]) + alpha_l[nl2] * ov;
                    if (FINAL) outF[(size_t)n * 160 + 64 + k * 3 + i2] = v;
                    else       outVb[(size_t)n * 96 + i2 * 32 + k] = f2bf(v * gate_l[nl2][k]);
                }
            }
        }
    }
}

// ---------------------------------------------------------------------------
extern "C" void kernel_launch(void* const* d_in, const int* in_sizes, int n_in,
                              void* d_out, int out_size, void* d_ws, size_t ws_size,
                              hipStream_t stream)
{
    const float* node_s = (const float*)d_in[0];
    const float* node_v = (const float*)d_in[1];
    const float* attr   = (const float*)d_in[2];
    const int*   esrc   = (const int*)d_in[3];
    const int*   edst   = (const int*)d_in[4];
    const float* esh    = (const float*)d_in[5];
    const float* esc    = (const float*)d_in[6];
    const float* W[18];
    for (int i = 0; i < 18; i++) W[i] = (const float*)d_in[7 + i];
    // per layer: 0 sc_s, 1 sc_v, 2 lin1_s, 3 lin1_v, 4 fc1, 5 fc2, 6 lin2_s, 7 lin2_v, 8 alpha

    const int N = in_sizes[0] / 64;
    const int E = in_sizes[3];
    const int NB = (N + 255) / 256;

    char* p = (char*)d_ws;
    unsigned short* xsb  = (unsigned short*)p; p += (size_t)N * 64 * 2;
    unsigned short* xvpb = (unsigned short*)p; p += (size_t)N * 96 * 2;
    unsigned short* hsb  = (unsigned short*)p; p += (size_t)N * 64 * 2;
    unsigned short* hvbb = (unsigned short*)p; p += (size_t)N * 96 * 2;
    unsigned short* Msb  = (unsigned short*)p; p += (size_t)N * 96 * 2;
    unsigned short* Mvb  = (unsigned short*)p; p += (size_t)N * 288 * 2;
    unsigned short* scs  = (unsigned short*)p; p += (size_t)N * 96 * 2;
    unsigned short* scv  = (unsigned short*)p; p += (size_t)N * 96 * 2;
    unsigned short* wsb1 = (unsigned short*)p; p += 160 * 64 * 2;
    unsigned short* wsb2 = (unsigned short*)p; p += 128 * 64 * 2;
    unsigned short* wvb1 = (unsigned short*)p; p += 64 * 32 * 2;
    unsigned short* wvb2 = (unsigned short*)p; p += 64 * 32 * 2;
    unsigned short* wfb1 = (unsigned short*)p; p += 192 * 64 * 2;
    unsigned short* wfb2 = (unsigned short*)p; p += 192 * 64 * 2;
    unsigned short* wob1 = (unsigned short*)p; p += 112 * 96 * 2;
    unsigned short* wob2 = (unsigned short*)p; p += 80 * 96 * 2;
    unsigned short* wv2b1 = (unsigned short*)p; p += 32 * 96 * 2;
    unsigned short* wv2b2 = (unsigned short*)p; p += 32 * 96 * 2;
    int* cnt    = (int*)p; p += (size_t)N * 4;
    int* cursor = (int*)p; p += (size_t)N * 4;
    int* basei  = (int*)p; p += (size_t)N * 4;
    int* partial = (int*)p; p += (size_t)NB * 4;
    p = (char*)(((size_t)p + 255) & ~(size_t)255);
    int* order   = (int*)p; p += (size_t)E * 4;
    int* src_ord = (int*)p; p += (size_t)E * 4;
    p = (char*)(((size_t)p + 15) & ~(size_t)15);
    float4* sh_ord = (float4*)p; p += (size_t)E * 16;
    unsigned short* esc_ordb = (unsigned short*)p; p += (size_t)E * 20;
    p = (char*)(((size_t)p + 255) & ~(size_t)255);
    const size_t used_fixed = (size_t)(p - (char*)d_ws);

    // adaptive: pick smallest NQ whose wbuf fits
    int NQ = 4;
    size_t cap = 0;
    {
        const int cands[3] = {1, 2, 4};
        for (int ci = 0; ci < 3; ci++) {
            const int c = cands[ci];
            size_t cc = (c == 1) ? (size_t)E : ((size_t)E / c) * 9 / 8 + 256;
            if (used_fixed + cc * 384 <= ws_size) { NQ = c; cap = cc; break; }
        }
        if (cap == 0) { NQ = 4; cap = ((size_t)E / 4) * 9 / 8 + 256; }
    }
    unsigned* wbuf12      = (unsigned*)p;       p += cap * 256;
    unsigned short* wbufB = (unsigned short*)p; p += cap * 128;

    const int nb  = (N + 63) / 64;
    const int ebk = (E + 255) / 256;
    const int Q   = (N + NQ - 1) / NQ;
    const int qb  = (Q + 3) / 4;
    const int emb = (int)((cap + 63) / 64);

    // ---- prep + CSR build
    hipMemsetAsync(cnt, 0, (size_t)2 * N * sizeof(int), stream);  // cnt + cursor
    k_prep_nodes<<<2048, 256, 0, stream>>>(node_s, node_v, edst, xsb, xvpb, cnt, N, E);
    k_prep_w<96><<<32, 256, 0, stream>>>(W[2], W[0], W[3], W[1], W[5], W[6], W[7], W[8],
                                         wsb1, wvb1, wfb1, wob1, wv2b1);
    k_prep_w<64><<<32, 256, 0, stream>>>(W[11], W[9], W[12], W[10], W[14], W[15], W[16], W[17],
                                         wsb2, wvb2, wfb2, wob2, wv2b2);
    k_scan1<<<NB, 256, 0, stream>>>(cnt, partial, N);
    k_scan2<<<1, 1024, 0, stream>>>(partial, NB);
    k_scan3<<<NB, 256, 0, stream>>>(cnt, partial, basei, N);
    k_order<<<ebk, 256, 0, stream>>>(edst, basei, cursor, order, E);
    k_gather<<<ebk, 256, 0, stream>>>(order, esrc, esh, esc,
                                      src_ord, sh_ord, esc_ordb, E);

    // ---- layer 1
    k_node_mfma<96><<<nb, 256, 0, stream>>>(xsb, xvpb, attr, wsb1, wvb1,
                                            hsb, hvbb, scs, scv, N);
    for (int q = 0; q < NQ; q++) {
        const int n0 = q * Q, n1 = min(N, (q + 1) * Q);
        if (n0 >= n1) break;
        k_edge_mlp<<<emb, 256, 0, stream>>>(esc_ordb, basei, W[4], wfb1,
                                            wbuf12, wbufB, n0, n1, N, E, (int)cap);
        k_agg<<<qb, 256, 0, stream>>>(hsb, hvbb, src_ord, sh_ord, basei, cnt,
                                      wbuf12, wbufB, Msb, Mvb, n0, n1, N, E);
    }
    k_node_out<96, false><<<nb, 256, 0, stream>>>(Msb, Mvb, attr, scs, scv,
                                                  wob1, wv2b1,
                                                  nullptr, xsb, xvpb, N);
    // ---- layer 2
    k_node_mfma<64><<<nb, 256, 0, stream>>>(xsb, xvpb, attr, wsb2, wvb2,
                                            hsb, hvbb, scs, scv, N);
    for (int q = 0; q < NQ; q++) {
        const int n0 = q * Q, n1 = min(N, (q + 1) * Q);
        if (n0 >= n1) break;
        k_edge_mlp<<<emb, 256, 0, stream>>>(esc_ordb, basei, W[13], wfb2,
                                            wbuf12, wbufB, n0, n1, N, E, (int)cap);
        k_agg<<<qb, 256, 0, stream>>>(hsb, hvbb, src_ord, sh_ord, basei, cnt,
                                      wbuf12, wbufB, Msb, Mvb, n0, n1, N, E);
    }
    k_node_out<64, true><<<nb, 256, 0, stream>>>(Msb, Mvb, attr, scs, scv,
                                                 wob2, wv2b2,
                                                 (float*)d_out, nullptr, nullptr, N);
}

// Round 12
// 465.567 us; speedup vs baseline: 2.8874x; 1.1719x over previous
//
#include <hip/hip_runtime.h>
#include <hip/hip_bf16.h>

#define INV_SQRT10 0.31622776601683794f
#define INV_SQRT64 0.125f
#define INV_SQRT32 0.17677669529663687f
#define INV_SQRT96 0.10206207261596575f
#define INV_SQRT3  0.5773502691896258f

typedef __attribute__((ext_vector_type(4))) float f32x4;
typedef __attribute__((ext_vector_type(8))) short bf16x8;

__device__ __forceinline__ unsigned short f2bf(float x) {
    return __builtin_bit_cast(unsigned short, (__hip_bfloat16)x);
}
__device__ __forceinline__ float bf2f(unsigned short u) {
    union { unsigned u; float f; } v; v.u = ((unsigned)u) << 16;
    return v.f;
}

// ---------------------------------------------------------------------------
// prep: node features -> bf16 (xs N x 64; xvp plane-major) + degree count
// ---------------------------------------------------------------------------
__global__ __launch_bounds__(256) void k_prep_nodes(
    const float* __restrict__ ns, const float* __restrict__ nv,
    const int* __restrict__ dst,
    unsigned short* __restrict__ xsb, unsigned short* __restrict__ xvpb,
    int* __restrict__ cnt, int N, int E)
{
    const int gid = blockIdx.x * 256 + threadIdx.x, gs = gridDim.x * 256;
    for (int i = gid; i < N * 64; i += gs) xsb[i] = f2bf(ns[i]);
    for (int i = gid; i < N * 96; i += gs) {
        const int n = i / 96, rem = i - n * 96;
        const int ic = rem >> 5, u = rem & 31;
        xvpb[i] = f2bf(nv[(size_t)n * 96 + u * 3 + ic]);
    }
    for (int i = gid; i < E; i += gs) atomicAdd(&cnt[dst[i]], 1);
}

// ---------------------------------------------------------------------------
// prep: weights -> bf16 panels.
// ---------------------------------------------------------------------------
template <int OS>
__global__ __launch_bounds__(256) void k_prep_w(
    const float* __restrict__ Wl1s, const float* __restrict__ Wscs,
    const float* __restrict__ Wl1v, const float* __restrict__ Wscv,
    const float* __restrict__ Wfc2,
    const float* __restrict__ W2s, const float* __restrict__ W2v,
    const float* __restrict__ Wa,
    unsigned short* __restrict__ wsb, unsigned short* __restrict__ wvb,
    unsigned short* __restrict__ wfb,
    unsigned short* __restrict__ wob, unsigned short* __restrict__ wv2b)
{
    constexpr int NC1 = 64 + OS;
    constexpr int PC1 = ((OS + 16 + 15) / 16) * 16;   // 112 (OS=96) / 80 (OS=64)
    const int gid = blockIdx.x * 256 + threadIdx.x, gs = gridDim.x * 256;
    for (int i = gid; i < NC1 * 64; i += gs) {
        const int c = i >> 6, k = i & 63;
        const float v = (c < 64) ? Wl1s[k * 64 + c] : Wscs[k * OS + (c - 64)];
        wsb[i] = f2bf(v);
    }
    for (int i = gid; i < 64 * 32; i += gs) {
        const int c = i >> 5, u = i & 31;
        const float v = (c < 32) ? Wl1v[u * 32 + c] : Wscv[u * 32 + (c - 32)];
        wvb[i] = f2bf(v);
    }
    for (int i = gid; i < 192 * 64; i += gs) {
        const int c = i >> 6, k = i & 63;
        wfb[i] = f2bf(Wfc2[k * 192 + c]);
    }
    for (int i = gid; i < PC1 * 96; i += gs) {
        const int c = i / 96, u = i - c * 96;
        float v = 0.f;
        if (c < OS) v = W2s[u * OS + c];
        else if (c == OS) v = Wa[u];
        wob[i] = f2bf(v);
    }
    for (int i = gid; i < 32 * 96; i += gs) {
        const int c = i / 96, u = i - c * 96;
        wv2b[i] = f2bf(W2v[u * 32 + c]);
    }
}

// ---------------------------------------------------------------------------
// Hierarchical exclusive scan of cnt -> base.
// ---------------------------------------------------------------------------
__global__ __launch_bounds__(256) void k_scan1(const int* __restrict__ cnt,
                                               int* __restrict__ partial, int N)
{
    __shared__ int lds[256];
    const int t = threadIdx.x, i = blockIdx.x * 256 + t;
    int v = (i < N) ? cnt[i] : 0;
    lds[t] = v;
    __syncthreads();
    for (int off = 128; off > 0; off >>= 1) {
        if (t < off) lds[t] += lds[t + off];
        __syncthreads();
    }
    if (t == 0) partial[blockIdx.x] = lds[0];
}

__global__ __launch_bounds__(1024) void k_scan2(int* __restrict__ partial, int NB)
{
    __shared__ int lds[1024];
    const int t = threadIdx.x;
    int v = (t < NB) ? partial[t] : 0;
    lds[t] = v;
    __syncthreads();
    for (int off = 1; off < 1024; off <<= 1) {
        int w = (t >= off) ? lds[t - off] : 0;
        __syncthreads();
        lds[t] += w;
        __syncthreads();
    }
    if (t < NB) partial[t] = lds[t] - v;   // exclusive
}

__global__ __launch_bounds__(256) void k_scan3(const int* __restrict__ cnt,
                                               const int* __restrict__ partial,
                                               int* __restrict__ base, int N)
{
    __shared__ int lds[256];
    const int t = threadIdx.x, i = blockIdx.x * 256 + t;
    int v = (i < N) ? cnt[i] : 0;
    lds[t] = v;
    __syncthreads();
    for (int off = 1; off < 256; off <<= 1) {
        int w = (t >= off) ? lds[t - off] : 0;
        __syncthreads();
        lds[t] += w;
        __syncthreads();
    }
    if (i < N) base[i] = partial[blockIdx.x] + lds[t] - v;
}

// ---------------------------------------------------------------------------
// order: scatter only the permutation (4B scattered writes).
// ---------------------------------------------------------------------------
__global__ __launch_bounds__(256) void k_order(
    const int* __restrict__ dst, const int* __restrict__ base,
    int* __restrict__ cursor, int* __restrict__ order, int E)
{
    int i = blockIdx.x * 256 + threadIdx.x;
    if (i < E) {
        const int d = dst[i];
        order[base[d] + atomicAdd(&cursor[d], 1)] = i;
    }
}

// ---------------------------------------------------------------------------
// gather: CSR-ordered src / sh (f32) / esc (bf16) with COALESCED writes.
// ---------------------------------------------------------------------------
__global__ __launch_bounds__(256) void k_gather(
    const int* __restrict__ order,
    const int* __restrict__ src, const float* __restrict__ sh,
    const float* __restrict__ esc,
    int* __restrict__ src_ord, float4* __restrict__ sh_ord,
    unsigned short* __restrict__ esc_ordb, int E)
{
    int pos = blockIdx.x * 256 + threadIdx.x;
    if (pos < E) {
        const int e = order[pos];
        src_ord[pos] = src[e];
        sh_ord[pos] = ((const float4*)sh)[e];
        const float* ep = esc + (size_t)e * 10;
        unsigned short* eo = esc_ordb + (size_t)pos * 10;
        #pragma unroll
        for (int q = 0; q < 10; q++) eo[q] = f2bf(ep[q]);
    }
}

// ---------------------------------------------------------------------------
// K1: node linears, register-only MFMA. 64 nodes/block, 4 waves.
// ---------------------------------------------------------------------------
template <int OS>
__global__ __launch_bounds__(256) void k_node_mfma(
    const unsigned short* __restrict__ xsb, const unsigned short* __restrict__ xvpb,
    const float* __restrict__ attr,
    const unsigned short* __restrict__ wsb, const unsigned short* __restrict__ wvb,
    unsigned short* __restrict__ hsb, unsigned short* __restrict__ hvbb,
    unsigned short* __restrict__ scs, unsigned short* __restrict__ scv, int N)
{
    constexpr int NC1 = 64 + OS;
    constexpr int CT1 = NC1 / 16;
    __shared__ float attr_l[64];
    const int tid = threadIdx.x;
    const int n0 = blockIdx.x * 64;
    if (tid < 64) attr_l[tid] = (n0 + tid < N) ? attr[n0 + tid] : 0.f;
    __syncthreads();
    const int wv = tid >> 6, lane = tid & 63;
    const int mrow = lane & 15, kg = lane >> 4;

    {
        const int rbase = wv * 16;
        const int r = rbase + mrow;
        const int rc = min(n0 + r, N - 1);
        const bf16x8 a0 = *(const bf16x8*)(xsb + (size_t)rc * 64 + kg * 8);
        const bf16x8 a1 = *(const bf16x8*)(xsb + (size_t)rc * 64 + 32 + kg * 8);
        f32x4 acc[CT1];
        #pragma unroll
        for (int t = 0; t < CT1; t++) acc[t] = (f32x4){0.f, 0.f, 0.f, 0.f};
        #pragma unroll
        for (int t = 0; t < CT1; t++) {
            const int c = t * 16 + mrow;
            const bf16x8 b0 = *(const bf16x8*)(wsb + c * 64 + kg * 8);
            const bf16x8 b1 = *(const bf16x8*)(wsb + c * 64 + 32 + kg * 8);
            acc[t] = __builtin_amdgcn_mfma_f32_16x16x32_bf16(a0, b0, acc[t], 0, 0, 0);
            acc[t] = __builtin_amdgcn_mfma_f32_16x16x32_bf16(a1, b1, acc[t], 0, 0, 0);
        }
        #pragma unroll
        for (int t = 0; t < CT1; t++) {
            const int c = t * 16 + mrow;
            #pragma unroll
            for (int rg = 0; rg < 4; rg++) {
                const int row = rbase + kg * 4 + rg;
                const int n = n0 + row;
                if (n < N) {
                    const float v = acc[t][rg] * INV_SQRT64 * attr_l[row];
                    if (c < 64) hsb[(size_t)n * 64 + c] = f2bf(v);
                    else        scs[(size_t)n * OS + (c - 64)] = f2bf(v);
                }
            }
        }
    }
    #pragma unroll
    for (int j = 0; j < 3; j++) {
        const int rbase = (wv * 3 + j) * 16;
        const int rv = rbase + mrow;
        const int ic = rv >> 6, nloc = rv & 63;
        const int nc = min(n0 + nloc, N - 1);
        const bf16x8 a = *(const bf16x8*)(xvpb + (size_t)nc * 96 + ic * 32 + kg * 8);
        f32x4 acc2[4];
        #pragma unroll
        for (int t = 0; t < 4; t++) acc2[t] = (f32x4){0.f, 0.f, 0.f, 0.f};
        #pragma unroll
        for (int t = 0; t < 4; t++) {
            const int c = t * 16 + mrow;
            const bf16x8 b = *(const bf16x8*)(wvb + c * 32 + kg * 8);
            acc2[t] = __builtin_amdgcn_mfma_f32_16x16x32_bf16(a, b, acc2[t], 0, 0, 0);
        }
        #pragma unroll
        for (int t = 0; t < 4; t++) {
            const int c = t * 16 + mrow;
            #pragma unroll
            for (int rg = 0; rg < 4; rg++) {
                const int rv2 = rbase + kg * 4 + rg;
                const int ic2 = rv2 >> 6, nl = rv2 & 63;
                const int n = n0 + nl;
                if (n < N) {
                    const float v = acc2[t][rg] * INV_SQRT32 * attr_l[nl];
                    if (c < 32) hvbb[(size_t)n * 96 + ic2 * 32 + c] = f2bf(v);
                    else        scv[(size_t)n * 96 + ic2 * 32 + (c - 32)] = f2bf(v);
                }
            }
        }
    }
}

// ---------------------------------------------------------------------------
// K2a: edge MLP. esc read direct from global (4-lane broadcast); Wfc2 panel
// staged into swizzled LDS once per block; packed per-lane stores.
// ---------------------------------------------------------------------------
__global__ __launch_bounds__(256) void k_edge_mlp(
    const unsigned short* __restrict__ esc_ordb, const int* __restrict__ base,
    const float* __restrict__ Wfc1, const unsigned short* __restrict__ wfb,
    unsigned* __restrict__ wbuf12, unsigned short* __restrict__ wbufB,
    int n0, int n1, int N, int E, int cap)
{
    __shared__ float w1_l[640];
    __shared__ __align__(16) char hb[64 * 64 * 2];    // [row][k] bf16 ^((r&7)<<4)
    __shared__ __align__(16) char wf_l[192 * 64 * 2]; // [c][k] bf16 ^((c&7)<<4)
    const int tid = threadIdx.x;
    const int lo = (n0 == 0) ? 0 : base[n0];
    const int hi = (n1 >= N) ? E : base[n1];
    const int p0 = lo + blockIdx.x * 64;
    if (p0 >= hi) return;

    for (int i = tid; i < 640; i += 256) w1_l[i] = Wfc1[i];
    for (int i = tid; i < 1536; i += 256) {          // 16B chunks of wfb
        const int c = i >> 3, k16 = i & 7;
        const uint4 v = *(const uint4*)(wfb + c * 64 + k16 * 8);
        *(uint4*)(wf_l + (((c << 7) + (k16 << 4)) ^ ((c & 7) << 4))) = v;
    }
    // ---- per-thread esc read (broadcast across the 4 threads of each edge)
    const int r = tid >> 2, c0 = (tid & 3) << 4;
    float ev[10];
    {
        const int rc = min(p0 + r, E - 1);
        const unsigned* ep = (const unsigned*)(esc_ordb + (size_t)rc * 10);
        #pragma unroll
        for (int q = 0; q < 5; q++) {
            const unsigned u = ep[q];
            ev[2 * q]     = bf2f((unsigned short)(u & 0xFFFF));
            ev[2 * q + 1] = bf2f((unsigned short)(u >> 16));
        }
    }
    __syncthreads();
    // ---- h = silu(esc @ Wfc1 / sqrt10): thread -> edge r, cols c0..c0+15
    {
        float hval[16];
        #pragma unroll
        for (int c = 0; c < 16; c++) {
            float acc = 0.f;
            #pragma unroll
            for (int q = 0; q < 10; q++) acc += ev[q] * w1_l[q * 64 + c0 + c];
            acc *= INV_SQRT10;
            hval[c] = acc / (1.f + __expf(-acc));
        }
        unsigned pk[8];
        #pragma unroll
        for (int j = 0; j < 8; j++)
            pk[j] = (unsigned)f2bf(hval[2 * j]) | ((unsigned)f2bf(hval[2 * j + 1]) << 16);
        const int swz = (r & 7) << 4;
        const int b0 = (r << 7) + (c0 << 1);
        *(uint4*)(hb + (b0 ^ swz)) = make_uint4(pk[0], pk[1], pk[2], pk[3]);
        *(uint4*)(hb + ((b0 + 16) ^ swz)) = make_uint4(pk[4], pk[5], pk[6], pk[7]);
    }
    __syncthreads();
    // ---- MFMA: wave wv -> rows [wv*16, +16), 12 col-tiles, K=64 (B from LDS)
    const int wv = tid >> 6, lane = tid & 63;
    const int mrow = lane & 15, kgrp = lane >> 4;
    f32x4 acc[12];
    #pragma unroll
    for (int t = 0; t < 12; t++) acc[t] = (f32x4){0.f, 0.f, 0.f, 0.f};
    #pragma unroll
    for (int kc = 0; kc < 2; kc++) {
        const int rr = wv * 16 + mrow;
        const int abyte = ((rr << 7) + (kc << 6) + (kgrp << 4)) ^ ((rr & 7) << 4);
        const bf16x8 afrag = *(const bf16x8*)(hb + abyte);
        #pragma unroll
        for (int t = 0; t < 12; t++) {
            const int c = t * 16 + mrow;
            const int bbyte = ((c << 7) + (kc << 6) + (kgrp << 4)) ^ ((c & 7) << 4);
            const bf16x8 bfrag = *(const bf16x8*)(wf_l + bbyte);
            acc[t] = __builtin_amdgcn_mfma_f32_16x16x32_bf16(afrag, bfrag, acc[t], 0, 0, 0);
        }
    }
    #pragma unroll
    for (int rg = 0; rg < 4; rg++) {
        const int rloc = wv * 16 + kgrp * 4 + rg;
        const int pos = p0 + rloc;
        if (pos < hi && (pos - lo) < cap) {
            uint4 pk12;
            pk12.x = (unsigned)f2bf(acc[0][rg] * INV_SQRT64) | ((unsigned)f2bf(acc[4][rg] * INV_SQRT64) << 16);
            pk12.y = (unsigned)f2bf(acc[1][rg] * INV_SQRT64) | ((unsigned)f2bf(acc[5][rg] * INV_SQRT64) << 16);
            pk12.z = (unsigned)f2bf(acc[2][rg] * INV_SQRT64) | ((unsigned)f2bf(acc[6][rg] * INV_SQRT64) << 16);
            pk12.w = (unsigned)f2bf(acc[3][rg] * INV_SQRT64) | ((unsigned)f2bf(acc[7][rg] * INV_SQRT64) << 16);
            ushort4 pkB;
            pkB.x = f2bf(acc[8][rg] * INV_SQRT64);
            pkB.y = f2bf(acc[9][rg] * INV_SQRT64);
            pkB.z = f2bf(acc[10][rg] * INV_SQRT64);
            pkB.w = f2bf(acc[11][rg] * INV_SQRT64);
            *(uint4*)(wbuf12 + (size_t)(pos - lo) * 64 + mrow * 4) = pk12;
            *(ushort4*)(wbufB + (size_t)(pos - lo) * 64 + mrow * 4) = pkB;
        }
    }
}

// ---------------------------------------------------------------------------
// K2b: aggregation. wave-per-dst-node over CSR; depth-2 software pipeline
// (src index prefetched two ahead). Writes deg-normalized Msb/Mvb (bf16).
// ---------------------------------------------------------------------------
__global__ __launch_bounds__(256) void k_agg(
    const unsigned short* __restrict__ hsb, const unsigned short* __restrict__ hvbb,
    const int* __restrict__ src_ord, const float4* __restrict__ sh_ord,
    const int* __restrict__ base, const int* __restrict__ cnt,
    const unsigned* __restrict__ wbuf12, const unsigned short* __restrict__ wbufB,
    unsigned short* __restrict__ Msb, unsigned short* __restrict__ Mvb,
    int n0, int n1, int N, int E)
{
    const int wave = threadIdx.x >> 6, lane = threadIdx.x & 63;
    const int n = n0 + blockIdx.x * 4 + wave;
    if (n >= n1) return;
    const int lo = (n0 == 0) ? 0 : base[n0];
    const int cidx = (lane & 15) * 4 + (lane >> 4);

    float aS = 0.f, aSB = 0.f;
    float aV0 = 0.f, aV1 = 0.f, aV2 = 0.f;
    float aB0 = 0.f, aB1 = 0.f, aB2 = 0.f;
    const int b0 = base[n];
    const int c_ = cnt[n];
    const size_t wb = (size_t)(b0 - lo) * 64;

    // pipeline state A (current) and next src index two ahead
    unsigned p12A = 0; float wBA = 0.f, gsA = 0.f;
    float gv0A = 0.f, gv1A = 0.f, gv2A = 0.f;
    float4 s4A = make_float4(0.f, 0.f, 0.f, 0.f);
    int s2 = 0;
    if (c_ > 0) {
        const int s1 = src_ord[b0];
        s2 = (c_ > 1) ? src_ord[b0 + 1] : 0;
        p12A = wbuf12[wb + cidx];
        wBA = bf2f(wbufB[wb + cidx]);
        gsA = bf2f(hsb[(size_t)s1 * 64 + lane]);
        if (lane < 32) {
            gv0A = bf2f(hvbb[(size_t)s1 * 96 + lane]);
            gv1A = bf2f(hvbb[(size_t)s1 * 96 + 32 + lane]);
            gv2A = bf2f(hvbb[(size_t)s1 * 96 + 64 + lane]);
        }
        s4A = sh_ord[b0];
    }
    for (int j = 0; j < c_; ++j) {
        // issue loads for j+1 (s2 already resident)
        unsigned p12B = 0; float wBB = 0.f, gsB = 0.f;
        float gv0B = 0.f, gv1B = 0.f, gv2B = 0.f;
        float4 s4B = make_float4(0.f, 0.f, 0.f, 0.f);
        if (j + 1 < c_) {
            p12B = wbuf12[wb + (size_t)(j + 1) * 64 + cidx];
            wBB = bf2f(wbufB[wb + (size_t)(j + 1) * 64 + cidx]);
            gsB = bf2f(hsb[(size_t)s2 * 64 + lane]);
            if (lane < 32) {
                gv0B = bf2f(hvbb[(size_t)s2 * 96 + lane]);
                gv1B = bf2f(hvbb[(size_t)s2 * 96 + 32 + lane]);
                gv2B = bf2f(hvbb[(size_t)s2 * 96 + 64 + lane]);
            }
            s4B = sh_ord[b0 + j + 1];
        }
        const int s2n = (j + 2 < c_) ? src_ord[b0 + j + 2] : 0;
        // accumulate A
        {
            const float w1 = bf2f((unsigned short)(p12A & 0xFFFF));
            const float w2 = bf2f((unsigned short)(p12A >> 16));
            const float gvdot = gv0A * s4A.y + gv1A * s4A.z + gv2A * s4A.w;
            const float gvd = __shfl(gvdot, lane & 31);
            aS  += gsA * s4A.x * w1;
            aSB += gvd * INV_SQRT3 * wBA;
            aV0 += gsA * s4A.y * w2;
            aV1 += gsA * s4A.z * w2;
            aV2 += gsA * s4A.w * w2;
            aB0 += gv0A * s4A.x * wBA;
            aB1 += gv1A * s4A.x * wBA;
            aB2 += gv2A * s4A.x * wBA;
        }
        // rotate
        p12A = p12B; wBA = wBB; gsA = gsB;
        gv0A = gv0B; gv1A = gv1B; gv2A = gv2B;
        s4A = s4B; s2 = s2n;
    }
    const float invd = 1.f / (float)max(c_, 1);
    unsigned short* msp = Msb + (size_t)n * 96;
    unsigned short* mvp = Mvb + (size_t)n * 3 * 96;
    msp[lane] = f2bf(aS * invd);
    if (lane >= 32) msp[64 + (lane - 32)] = f2bf(aSB * invd);
    mvp[0 * 96 + lane] = f2bf(aV0 * invd);
    mvp[1 * 96 + lane] = f2bf(aV1 * invd);
    mvp[2 * 96 + lane] = f2bf(aV2 * invd);
    if (lane < 32) {
        mvp[0 * 96 + 64 + lane] = f2bf(aB0 * invd);
        mvp[1 * 96 + 64 + lane] = f2bf(aB1 * invd);
        mvp[2 * 96 + 64 + lane] = f2bf(aB2 * invd);
    }
}

// ---------------------------------------------------------------------------
// K3: node finalize as MFMA. 64 nodes/block, 4 waves. scs/scv bf16.
// ---------------------------------------------------------------------------
template <int OS, bool FINAL>
__global__ __launch_bounds__(256) void k_node_out(
    const unsigned short* __restrict__ Msb, const unsigned short* __restrict__ Mvb,
    const float* __restrict__ attr,
    const unsigned short* __restrict__ scs, const unsigned short* __restrict__ scv,
    const unsigned short* __restrict__ wob, const unsigned short* __restrict__ wv2b,
    float* __restrict__ outF,
    unsigned short* __restrict__ outSb, unsigned short* __restrict__ outVb, int N)
{
    constexpr int CT1 = (OS + 16 + 15) / 16;   // 7 (OS=96) / 5 (OS=64)
    constexpr int TA = OS / 16;                // tile holding alpha col (mrow==0)
    __shared__ float attr_l[64];
    __shared__ float alpha_l[64];
    __shared__ float gate_l[64][32];
    const int tid = threadIdx.x;
    const int n0 = blockIdx.x * 64;
    if (tid < 64) attr_l[tid] = (n0 + tid < N) ? attr[n0 + tid] : 0.f;
    __syncthreads();
    const int wv = tid >> 6, lane = tid & 63;
    const int mrow = lane & 15, kg = lane >> 4;

    // ---- GEMM1
    const int rbase = wv * 16;
    const int rc = min(n0 + rbase + mrow, N - 1);
    f32x4 acc[CT1];
    #pragma unroll
    for (int t = 0; t < CT1; t++) acc[t] = (f32x4){0.f, 0.f, 0.f, 0.f};
    #pragma unroll
    for (int kc = 0; kc < 3; kc++) {
        const bf16x8 a = *(const bf16x8*)(Msb + (size_t)rc * 96 + kc * 32 + kg * 8);
        #pragma unroll
        for (int t = 0; t < CT1; t++) {
            const bf16x8 b = *(const bf16x8*)(wob + (size_t)(t * 16 + mrow) * 96 + kc * 32 + kg * 8);
            acc[t] = __builtin_amdgcn_mfma_f32_16x16x32_bf16(a, b, acc[t], 0, 0, 0);
        }
    }
    if (mrow == 0) {
        #pragma unroll
        for (int rg = 0; rg < 4; rg++) {
            const int row = rbase + kg * 4 + rg;
            alpha_l[row] = acc[TA][rg] * INV_SQRT96 * attr_l[row];
        }
    }
    __syncthreads();
    // ---- epilogue 1
    #pragma unroll
    for (int t = 0; t < CT1; t++) {
        const int c = t * 16 + mrow;
        if (c < OS) {
            #pragma unroll
            for (int rg = 0; rg < 4; rg++) {
                const int row = rbase + kg * 4 + rg;
                const int n = n0 + row;
                if (n < N) {
                    const float os = acc[t][rg] * INV_SQRT96 * attr_l[row];
                    const float s = bf2f(scs[(size_t)n * OS + c]) + alpha_l[row] * os;
                    if (FINAL) {
                        outF[(size_t)n * 160 + c] = s;
                    } else {
                        if (c < 64) outSb[(size_t)n * 64 + c] = f2bf(s / (1.f + __expf(-s)));
                        else        gate_l[row][c - 64] = 1.f / (1.f + __expf(-s));
                    }
                }
            }
        }
    }
    __syncthreads();
    // ---- GEMM2: rows rv = nloc*3+i (192), wave handles 3 row-tiles
    #pragma unroll
    for (int j = 0; j < 3; j++) {
        const int rb2 = (wv * 3 + j) * 16;
        const int rv = rb2 + mrow;
        const int nl = rv / 3, ii = rv - nl * 3;
        const int nc2 = min(n0 + nl, N - 1);
        f32x4 acc2[2];
        acc2[0] = (f32x4){0.f, 0.f, 0.f, 0.f};
        acc2[1] = (f32x4){0.f, 0.f, 0.f, 0.f};
        #pragma unroll
        for (int kc = 0; kc < 3; kc++) {
            const bf16x8 a = *(const bf16x8*)(Mvb + ((size_t)nc2 * 3 + ii) * 96 + kc * 32 + kg * 8);
            #pragma unroll
            for (int t = 0; t < 2; t++) {
                const bf16x8 b = *(const bf16x8*)(wv2b + (size_t)(t * 16 + mrow) * 96 + kc * 32 + kg * 8);
                acc2[t] = __builtin_amdgcn_mfma_f32_16x16x32_bf16(a, b, acc2[t], 0, 0, 0);
            }
        }
        #pragma unroll
        for (int t = 0; t < 2; t++) {
            const int k = t * 16 + mrow;
            #pragma unroll
            for (int rg = 0; rg < 4; rg++) {
                const int rv2 = rb2 + kg * 4 + rg;
                const int nl2 = rv2 / 3, i2 = rv2 - nl2 * 3;
                const int n = n0 + nl2;
                if (n < N) {
                    const float ov = acc2[t][rg] * INV_SQRT96 * attr_l[nl2];
                    const float v = bf2f(scv[(size_t)n * 96 + i2 * 32 + k]) + alpha_l[nl2] * ov;
                    if (FINAL) outF[(size_t)n * 160 + 64 + k * 3 + i2] = v;
                    else       outVb[(size_t)n * 96 + i2 * 32 + k] = f2bf(v * gate_l[nl2][k]);
                }
            }
        }
    }
}

// ---------------------------------------------------------------------------
extern "C" void kernel_launch(void* const* d_in, const int* in_sizes, int n_in,
                              void* d_out, int out_size, void* d_ws, size_t ws_size,
                              hipStream_t stream)
{
    const float* node_s = (const float*)d_in[0];
    const float* node_v = (const float*)d_in[1];
    const float* attr   = (const float*)d_in[2];
    const int*   esrc   = (const int*)d_in[3];
    const int*   edst   = (const int*)d_in[4];
    const float* esh    = (const float*)d_in[5];
    const float* esc    = (const float*)d_in[6];
    const float* W[18];
    for (int i = 0; i < 18; i++) W[i] = (const float*)d_in[7 + i];
    // per layer: 0 sc_s, 1 sc_v, 2 lin1_s, 3 lin1_v, 4 fc1, 5 fc2, 6 lin2_s, 7 lin2_v, 8 alpha

    const int N = in_sizes[0] / 64;
    const int E = in_sizes[3];
    const int NB = (N + 255) / 256;

    char* p = (char*)d_ws;
    unsigned short* xsb  = (unsigned short*)p; p += (size_t)N * 64 * 2;
    unsigned short* xvpb = (unsigned short*)p; p += (size_t)N * 96 * 2;
    unsigned short* hsb  = (unsigned short*)p; p += (size_t)N * 64 * 2;
    unsigned short* hvbb = (unsigned short*)p; p += (size_t)N * 96 * 2;
    unsigned short* Msb  = (unsigned short*)p; p += (size_t)N * 96 * 2;
    unsigned short* Mvb  = (unsigned short*)p; p += (size_t)N * 288 * 2;
    unsigned short* scs  = (unsigned short*)p; p += (size_t)N * 96 * 2;
    unsigned short* scv  = (unsigned short*)p; p += (size_t)N * 96 * 2;
    unsigned short* wsb1 = (unsigned short*)p; p += 160 * 64 * 2;
    unsigned short* wsb2 = (unsigned short*)p; p += 128 * 64 * 2;
    unsigned short* wvb1 = (unsigned short*)p; p += 64 * 32 * 2;
    unsigned short* wvb2 = (unsigned short*)p; p += 64 * 32 * 2;
    unsigned short* wfb1 = (unsigned short*)p; p += 192 * 64 * 2;
    unsigned short* wfb2 = (unsigned short*)p; p += 192 * 64 * 2;
    unsigned short* wob1 = (unsigned short*)p; p += 112 * 96 * 2;
    unsigned short* wob2 = (unsigned short*)p; p += 80 * 96 * 2;
    unsigned short* wv2b1 = (unsigned short*)p; p += 32 * 96 * 2;
    unsigned short* wv2b2 = (unsigned short*)p; p += 32 * 96 * 2;
    int* cnt    = (int*)p; p += (size_t)N * 4;
    int* cursor = (int*)p; p += (size_t)N * 4;
    int* basei  = (int*)p; p += (size_t)N * 4;
    int* partial = (int*)p; p += (size_t)NB * 4;
    p = (char*)(((size_t)p + 255) & ~(size_t)255);
    int* order   = (int*)p; p += (size_t)E * 4;
    int* src_ord = (int*)p; p += (size_t)E * 4;
    p = (char*)(((size_t)p + 15) & ~(size_t)15);
    float4* sh_ord = (float4*)p; p += (size_t)E * 16;
    unsigned short* esc_ordb = (unsigned short*)p; p += (size_t)E * 20;
    p = (char*)(((size_t)p + 255) & ~(size_t)255);
    const size_t used_fixed = (size_t)(p - (char*)d_ws);

    // adaptive: pick smallest NQ whose wbuf fits
    int NQ = 4;
    size_t cap = 0;
    {
        const int cands[3] = {1, 2, 4};
        for (int ci = 0; ci < 3; ci++) {
            const int c = cands[ci];
            size_t cc = (c == 1) ? (size_t)E : ((size_t)E / c) * 9 / 8 + 256;
            if (used_fixed + cc * 384 <= ws_size) { NQ = c; cap = cc; break; }
        }
        if (cap == 0) { NQ = 4; cap = ((size_t)E / 4) * 9 / 8 + 256; }
    }
    unsigned* wbuf12      = (unsigned*)p;       p += cap * 256;
    unsigned short* wbufB = (unsigned short*)p; p += cap * 128;

    const int nb  = (N + 63) / 64;
    const int ebk = (E + 255) / 256;
    const int Q   = (N + NQ - 1) / NQ;
    const int qb  = (Q + 3) / 4;
    const int emb = (int)((cap + 63) / 64);

    // ---- prep + CSR build
    hipMemsetAsync(cnt, 0, (size_t)2 * N * sizeof(int), stream);  // cnt + cursor
    k_prep_nodes<<<2048, 256, 0, stream>>>(node_s, node_v, edst, xsb, xvpb, cnt, N, E);
    k_prep_w<96><<<32, 256, 0, stream>>>(W[2], W[0], W[3], W[1], W[5], W[6], W[7], W[8],
                                         wsb1, wvb1, wfb1, wob1, wv2b1);
    k_prep_w<64><<<32, 256, 0, stream>>>(W[11], W[9], W[12], W[10], W[14], W[15], W[16], W[17],
                                         wsb2, wvb2, wfb2, wob2, wv2b2);
    k_scan1<<<NB, 256, 0, stream>>>(cnt, partial, N);
    k_scan2<<<1, 1024, 0, stream>>>(partial, NB);
    k_scan3<<<NB, 256, 0, stream>>>(cnt, partial, basei, N);
    k_order<<<ebk, 256, 0, stream>>>(edst, basei, cursor, order, E);
    k_gather<<<ebk, 256, 0, stream>>>(order, esrc, esh, esc,
                                      src_ord, sh_ord, esc_ordb, E);

    // ---- layer 1
    k_node_mfma<96><<<nb, 256, 0, stream>>>(xsb, xvpb, attr, wsb1, wvb1,
                                            hsb, hvbb, scs, scv, N);
    for (int q = 0; q < NQ; q++) {
        const int n0 = q * Q, n1 = min(N, (q + 1) * Q);
        if (n0 >= n1) break;
        k_edge_mlp<<<emb, 256, 0, stream>>>(esc_ordb, basei, W[4], wfb1,
                                            wbuf12, wbufB, n0, n1, N, E, (int)cap);
        k_agg<<<qb, 256, 0, stream>>>(hsb, hvbb, src_ord, sh_ord, basei, cnt,
                                      wbuf12, wbufB, Msb, Mvb, n0, n1, N, E);
    }
    k_node_out<96, false><<<nb, 256, 0, stream>>>(Msb, Mvb, attr, scs, scv,
                                                  wob1, wv2b1,
                                                  nullptr, xsb, xvpb, N);
    // ---- layer 2
    k_node_mfma<64><<<nb, 256, 0, stream>>>(xsb, xvpb, attr, wsb2, wvb2,
                                            hsb, hvbb, scs, scv, N);
    for (int q = 0; q < NQ; q++) {
        const int n0 = q * Q, n1 = min(N, (q + 1) * Q);
        if (n0 >= n1) break;
        k_edge_mlp<<<emb, 256, 0, stream>>>(esc_ordb, basei, W[13], wfb2,
                                            wbuf12, wbufB, n0, n1, N, E, (int)cap);
        k_agg<<<qb, 256, 0, stream>>>(hsb, hvbb, src_ord, sh_ord, basei, cnt,
                                      wbuf12, wbufB, Msb, Mvb, n0, n1, N, E);
    }
    k_node_out<64, true><<<nb, 256, 0, stream>>>(Msb, Mvb, attr, scs, scv,
                                                 wob2, wv2b2,
                                                 (float*)d_out, nullptr, nullptr, N);
}